// Round 1
// baseline (1511.982 us; speedup 1.0000x reference)
//
#include <hip/hip_runtime.h>
#include <hip/hip_bf16.h>
#include <math.h>

#define B_  4
#define N_  2048
#define C_  128
#define CIN 131
#define NS_ 64
#define H1_ 256
#define H2_ 128

// ---------------------------------------------------------------------------
// prep: transpose features (B,C,N)->(B,N,C); W1 (256,131)->W1t (132,256) with
// zero pad row 131; W2 (128,256)->W2t (256,128)
// ---------------------------------------------------------------------------
__global__ __launch_bounds__(256) void prep_kernel(
    const float* __restrict__ feat, const float* __restrict__ W1,
    const float* __restrict__ W2, float* __restrict__ feat_nc,
    float* __restrict__ W1t, float* __restrict__ W2t)
{
  int i = blockIdx.x * 256 + threadIdx.x;
  // features transpose: i = ((b*C)+c)*N + n  (coalesced read over n)
  {
    int n = i & (N_ - 1);
    int bc = i >> 11;
    int c = bc & (C_ - 1);
    int b = bc >> 7;
    feat_nc[((b << 11) + n) * C_ + c] = feat[i];
  }
  if (i < H1_ * CIN) {              // 33536
    int o = i / CIN, c = i - o * CIN;
    W1t[c * H1_ + o] = W1[i];
  }
  if (i < H1_) W1t[CIN * H1_ + i] = 0.0f;   // zero pad row c=131
  if (i < H2_ * H1_) {              // 32768
    int p = i >> 8, o = i & 255;
    W2t[o * H2_ + p] = W2[i];
  }
}

// ---------------------------------------------------------------------------
// ball query: one wave per (b,n) row, fp64 d2 (exact membership decisions),
// ordered first-NS selection via ballot prefix, pad with first hit.
// ---------------------------------------------------------------------------
__global__ __launch_bounds__(256) void ballquery_kernel(
    const float* __restrict__ xyz, int* __restrict__ idxout)
{
  __shared__ float  xl[N_ * 3];
  __shared__ double sq[N_];
  __shared__ int    ibuf[4][NS_];

  const int b  = blockIdx.x >> 9;          // 512 blocks per batch
  const int ng = blockIdx.x & 511;
  const int t  = threadIdx.x;
  const float* xb = xyz + b * N_ * 3;

  for (int i = t; i < N_ * 3; i += 256) xl[i] = xb[i];
  __syncthreads();
  for (int i = t; i < N_; i += 256) {
    double x = (double)xl[3*i], y = (double)xl[3*i+1], z = (double)xl[3*i+2];
    sq[i] = x*x + y*y + z*z;
  }
  __syncthreads();

  const int wv = t >> 6, lane = t & 63;
  const int n = ng * 4 + wv;
  const double xn = (double)xl[3*n], yn = (double)xl[3*n+1], zn = (double)xl[3*n+2];
  const double sn = sq[n];

  int cnt = 0;
  for (int mb = 0; mb < N_; mb += 64) {
    int m = mb + lane;
    double dot = xn*(double)xl[3*m] + yn*(double)xl[3*m+1] + zn*(double)xl[3*m+2];
    double d2 = (sn + sq[m]) - 2.0 * dot;
    bool hit = d2 < 0.0625;
    unsigned long long mask = __ballot(hit);
    int pos = __popcll(mask & ((1ULL << lane) - 1ULL));
    int slot = cnt + pos;
    if (hit && slot < NS_) ibuf[wv][slot] = m;
    cnt += (int)__popcll(mask);
    if (cnt >= NS_) break;
  }
  asm volatile("s_waitcnt lgkmcnt(0)" ::: "memory");
  int total = cnt < NS_ ? cnt : NS_;       // total >= 1 (self-hit, d2 == 0)
  int v = ibuf[wv][lane < total ? lane : 0];
  idxout[(b * N_ + n) * NS_ + lane] = v;
}

// ---------------------------------------------------------------------------
// MLP: one block per (b,n), 256 threads, 64 samples in two halves of 32.
// h[c](n,m) = (p_c[m] - q_c[n])^2 ; p = [xyz[m], feat[m]] ; q = [2*xyz[n], feat[n]]
// ---------------------------------------------------------------------------
__global__ __launch_bounds__(256, 2) void mlp_kernel(
    const float* __restrict__ xyz, const float* __restrict__ feat_nc,
    const float* __restrict__ W1t, const float* __restrict__ W2t,
    const float* __restrict__ W3,
    const float* __restrict__ g1, const float* __restrict__ b1,
    const float* __restrict__ g2, const float* __restrict__ b2,
    const float* __restrict__ g3, const float* __restrict__ b3,
    const int* __restrict__ idx, float* __restrict__ out)
{
  __shared__ __align__(16) float h_lds[32 * 132];   // [s][c], pad col 131 = 0
  __shared__ __align__(16) float a1_lds[32 * 256];
  __shared__ float a2_lds[32 * 129];                // stride 129: conflict-free col read
  __shared__ int   idx_lds[NS_];
  __shared__ float q_lds[132];

  const int bn = blockIdx.x;
  const int b = bn >> 11;
  const int n = bn & (N_ - 1);
  const int t = threadIdx.x;
  const float inv = 1.0f / sqrtf(1.0f + 1e-5f);

  if (t < NS_) idx_lds[t] = idx[bn * NS_ + t];
  if (t < CIN) {
    float qv = (t < 3) ? 2.0f * xyz[bn * 3 + t] : feat_nc[bn * C_ + (t - 3)];
    q_lds[t] = qv;
  }
  const float gi1 = g1[t] * inv, bb1 = b1[t];
  const int   p = t & (H2_ - 1), sh = (t >> 7) * 16;
  const float gi2 = g2[p] * inv, bb2 = b2[p];
  const float xn0 = xyz[bn*3+0], xn1 = xyz[bn*3+1], xn2 = xyz[bn*3+2];
  const float g3c = g3[0] * inv, b3c = b3[0];

  float num0 = 0.f, num1 = 0.f, num2 = 0.f, den = 0.f;
  __syncthreads();

  for (int s0 = 0; s0 < NS_; s0 += 32) {
    // ---- stage h (coalesced gathers of feat rows) ----
    for (int i = t; i < 32 * 132; i += 256) {
      int s = i / 132, c = i - s * 132;
      float hv = 0.0f;
      if (c < CIN) {
        int m = idx_lds[s0 + s];
        float pv = (c < 3) ? xyz[(b * N_ + m) * 3 + c]
                           : feat_nc[(b * N_ + m) * C_ + (c - 3)];
        float d = pv - q_lds[c];
        hv = d * d;
      }
      h_lds[i] = hv;
    }
    __syncthreads();

    // ---- layer 1: thread t owns output channel o=t, all 32 s at once ----
    {
      float acc[32];
      #pragma unroll
      for (int j = 0; j < 32; ++j) acc[j] = 0.0f;
      for (int c = 0; c < 132; c += 4) {
        float w0 = W1t[(c + 0) * H1_ + t];
        float w1 = W1t[(c + 1) * H1_ + t];
        float w2 = W1t[(c + 2) * H1_ + t];
        float w3 = W1t[(c + 3) * H1_ + t];
        #pragma unroll
        for (int j = 0; j < 32; ++j) {
          float4 hv = *reinterpret_cast<const float4*>(&h_lds[j * 132 + c]);
          acc[j] = fmaf(w0, hv.x, fmaf(w1, hv.y, fmaf(w2, hv.z, fmaf(w3, hv.w, acc[j]))));
        }
      }
      #pragma unroll
      for (int j = 0; j < 32; ++j) {
        float a = fmaf(gi1, acc[j], bb1);
        a1_lds[j * H1_ + t] = a > 0.0f ? a : 0.0f;
      }
    }
    __syncthreads();

    // ---- layer 2: thread (p, sh) covers 16 s ----
    {
      float acc[16];
      #pragma unroll
      for (int j = 0; j < 16; ++j) acc[j] = 0.0f;
      for (int o = 0; o < H1_; o += 4) {
        float w0 = W2t[(o + 0) * H2_ + p];
        float w1 = W2t[(o + 1) * H2_ + p];
        float w2 = W2t[(o + 2) * H2_ + p];
        float w3 = W2t[(o + 3) * H2_ + p];
        #pragma unroll
        for (int j = 0; j < 16; ++j) {
          float4 av = *reinterpret_cast<const float4*>(&a1_lds[(sh + j) * H1_ + o]);
          acc[j] = fmaf(w0, av.x, fmaf(w1, av.y, fmaf(w2, av.z, fmaf(w3, av.w, acc[j]))));
        }
      }
      #pragma unroll
      for (int j = 0; j < 16; ++j) {
        float a = fmaf(gi2, acc[j], bb2);
        a2_lds[(sh + j) * 129 + p] = a > 0.0f ? a : 0.0f;
      }
    }
    __syncthreads();

    // ---- layer 3 + weighted reduce (wave 0, lanes 0..31; one s per lane) ----
    if (t < 32) {
      float z3 = 0.0f;
      for (int pp = 0; pp < H2_; ++pp)
        z3 = fmaf(W3[pp], a2_lds[t * 129 + pp], z3);
      float wgt = fmaf(g3c, z3, b3c);
      wgt = wgt > 0.0f ? wgt : 0.0f;
      int m = idx_lds[s0 + t];
      float gx = xyz[(b * N_ + m) * 3 + 0] - xn0;
      float gy = xyz[(b * N_ + m) * 3 + 1] - xn1;
      float gz = xyz[(b * N_ + m) * 3 + 2] - xn2;
      float p0 = gx * wgt, p1 = gy * wgt, p2 = gz * wgt, p3 = wgt;
      #pragma unroll
      for (int off = 16; off > 0; off >>= 1) {
        p0 += __shfl_xor(p0, off);
        p1 += __shfl_xor(p1, off);
        p2 += __shfl_xor(p2, off);
        p3 += __shfl_xor(p3, off);
      }
      num0 += p0; num1 += p1; num2 += p2; den += p3;
    }
    __syncthreads();
  }

  if (t == 0) {
    out[(b * 3 + 0) * N_ + n] = num0 / den;
    out[(b * 3 + 1) * N_ + n] = num1 / den;
    out[(b * 3 + 2) * N_ + n] = num2 / den;
  }
}

extern "C" void kernel_launch(void* const* d_in, const int* in_sizes, int n_in,
                              void* d_out, int out_size, void* d_ws, size_t ws_size,
                              hipStream_t stream) {
  const float* xyz      = (const float*)d_in[0];
  const float* features = (const float*)d_in[1];
  const float* W1 = (const float*)d_in[2];
  const float* W2 = (const float*)d_in[3];
  const float* W3 = (const float*)d_in[4];
  const float* g1 = (const float*)d_in[5];
  const float* g2 = (const float*)d_in[6];
  const float* g3 = (const float*)d_in[7];
  const float* b1 = (const float*)d_in[8];
  const float* b2 = (const float*)d_in[9];
  const float* b3 = (const float*)d_in[10];
  float* out = (float*)d_out;

  char* ws = (char*)d_ws;
  float* feat_nc = (float*)ws;                                  // 4 MB
  int*   idx     = (int*)(ws + 4194304);                        // 2 MB
  float* W1t     = (float*)(ws + 4194304 + 2097152);            // 132*256*4
  float* W2t     = (float*)(ws + 4194304 + 2097152 + 135168);   // 256*128*4

  prep_kernel<<<dim3((B_ * C_ * N_) / 256), dim3(256), 0, stream>>>(
      features, W1, W2, feat_nc, W1t, W2t);
  ballquery_kernel<<<dim3(B_ * N_ / 4), dim3(256), 0, stream>>>(xyz, idx);
  mlp_kernel<<<dim3(B_ * N_), dim3(256), 0, stream>>>(
      xyz, feat_nc, W1t, W2t, W3, g1, b1, g2, b2, g3, b3, idx, out);
}

// Round 2
// 792.744 us; speedup vs baseline: 1.9073x; 1.9073x over previous
//
#include <hip/hip_runtime.h>
#include <math.h>

typedef _Float16 f16;
typedef _Float16 f16x8 __attribute__((ext_vector_type(8)));
typedef float f32x4 __attribute__((ext_vector_type(4)));

#define B_  4
#define N_  2048
#define C_  128
#define NS_ 64

// ---- workspace layout (bytes) ----
#define WS_FEATNC 0u          // B*N*C f32 = 4194304
#define WS_IDX    4194304u    // B*N*NS u16 = 1048576
#define WS_W1P    5242880u    // 5 slices * 2 limbs * 256*32 f16 = 163840
#define WS_W2P    5406720u    // 8 slices * 2 limbs * 128*32 f16 = 131072
// total 5537792 bytes

// ---- mlp LDS layout (bytes) ----
// h region (rows stride 384B, XOR-swizzled): overlaid later by a1 region
#define OFF_HHI   0           // 64*384 = 24576
#define OFF_HLO   24576       // 24576
#define OFF_A1HI  0           // 64*512 = 32768 (overlays h after GEMM1)
#define OFF_A1LO  32768       // 32768
#define OFF_W     65536       // double buffer 2*32768
#define OFF_A2    65536       // 64*528 f32 = 33792 (overlays W at the end)
#define OFF_IDX   131072      // 64*4
#define OFF_Q     131328      // 160*4
#define OFF_GX    131968      // 64*16
#define OFF_W3    132992      // 128*4
#define OFF_RED   133504      // 16*4
#define LDS_TOTAL 133632

__device__ __forceinline__ void gl_lds16(const char* gp, char* lp) {
  __builtin_amdgcn_global_load_lds(
      (const __attribute__((address_space(1))) unsigned int*)gp,
      (__attribute__((address_space(3))) unsigned int*)lp, 16, 0, 0);
}

// ---------------------------------------------------------------------------
// prep: feat (B,C,N)->(B,N,C) f32; W1 -> 5 K-slices x {hi,lo} [256 o][32 c]
// f16 XOR-swizzled; W2 -> 8 K-slices x {hi,lo} [128 p][32 o] f16 swizzled.
// Swizzle: byte ^= ((row&7)<<4) applied to (row*64 + col*2) — the exact LDS
// image, so mlp stages with linear global_load_lds.
// ---------------------------------------------------------------------------
__global__ __launch_bounds__(256) void prep_kernel(
    const float* __restrict__ feat, const float* __restrict__ W1,
    const float* __restrict__ W2, float* __restrict__ feat_nc,
    f16* __restrict__ W1p, f16* __restrict__ W2p)
{
  int i = blockIdx.x * 256 + threadIdx.x;
  {
    int n = i & (N_ - 1);
    int bc = i >> 11;
    int c = bc & (C_ - 1);
    int b = bc >> 7;
    feat_nc[(size_t)((b << 11) + n) * C_ + c] = feat[i];
  }
  if (i < 5 * 256 * 32) {
    int kc = i / 8192; int rem = i - kc * 8192; int o = rem >> 5; int cp = rem & 31;
    int c = kc * 32 + cp;
    float w = (c < 131) ? W1[o * 131 + c] : 0.0f;
    f16 hi = (f16)w; f16 lo = (f16)(w - (float)hi);
    unsigned byteoff = ((unsigned)(o * 64 + cp * 2)) ^ ((unsigned)((o & 7) << 4));
    char* base = (char*)W1p + (size_t)kc * 32768;
    *(f16*)(base + byteoff) = hi;
    *(f16*)(base + 16384 + byteoff) = lo;
  }
  if (i < 8 * 128 * 32) {
    int kk = i / 4096; int rem = i - kk * 4096; int p = rem >> 5; int op = rem & 31;
    int o = kk * 32 + op;
    float w = W2[p * 256 + o];
    f16 hi = (f16)w; f16 lo = (f16)(w - (float)hi);
    unsigned byteoff = ((unsigned)(p * 64 + op * 2)) ^ ((unsigned)((p & 7) << 4));
    char* base = (char*)W2p + (size_t)kk * 16384;
    *(f16*)(base + byteoff) = hi;
    *(f16*)(base + 8192 + byteoff) = lo;
  }
}

// ---------------------------------------------------------------------------
// ball query (unchanged, fp64-exact membership), output u16
// ---------------------------------------------------------------------------
__global__ __launch_bounds__(256) void ballquery_kernel(
    const float* __restrict__ xyz, unsigned short* __restrict__ idxout)
{
  __shared__ float  xl[N_ * 3];
  __shared__ double sq[N_];
  __shared__ int    ibuf[4][NS_];

  const int b  = blockIdx.x >> 9;
  const int ng = blockIdx.x & 511;
  const int t  = threadIdx.x;
  const float* xb = xyz + (size_t)b * N_ * 3;

  for (int i = t; i < N_ * 3; i += 256) xl[i] = xb[i];
  __syncthreads();
  for (int i = t; i < N_; i += 256) {
    double x = (double)xl[3*i], y = (double)xl[3*i+1], z = (double)xl[3*i+2];
    sq[i] = x*x + y*y + z*z;
  }
  __syncthreads();

  const int wv = t >> 6, lane = t & 63;
  const int n = ng * 4 + wv;
  const double xn = (double)xl[3*n], yn = (double)xl[3*n+1], zn = (double)xl[3*n+2];
  const double sn = sq[n];

  int cnt = 0;
  for (int mb = 0; mb < N_; mb += 64) {
    int m = mb + lane;
    double dot = xn*(double)xl[3*m] + yn*(double)xl[3*m+1] + zn*(double)xl[3*m+2];
    double d2 = (sn + sq[m]) - 2.0 * dot;
    bool hit = d2 < 0.0625;
    unsigned long long mask = __ballot(hit);
    int pos = __popcll(mask & ((1ULL << lane) - 1ULL));
    int slot = cnt + pos;
    if (hit && slot < NS_) ibuf[wv][slot] = m;
    cnt += (int)__popcll(mask);
    if (cnt >= NS_) break;
  }
  asm volatile("s_waitcnt lgkmcnt(0)" ::: "memory");
  int total = cnt < NS_ ? cnt : NS_;
  int v = ibuf[wv][lane < total ? lane : 0];
  idxout[((size_t)b * N_ + n) * NS_ + lane] = (unsigned short)v;
}

// ---------------------------------------------------------------------------
// MLP via f16 MFMA, 2-limb error-compensated split (hh + lh + hl terms).
// One block (4 waves, 256 thr) per (b,n). GEMM1: [64x256]xK480'; GEMM2:
// [64x128]xK768'. Weights double-buffered via global_load_lds; h and a1 limbs
// in XOR-swizzled LDS; GEMM3 + weighted mean on VALU.
// ---------------------------------------------------------------------------
__global__ __launch_bounds__(256, 1) void mlp_kernel(
    const float* __restrict__ xyz, const float* __restrict__ feat_nc,
    const char* __restrict__ w1p, const char* __restrict__ w2p,
    const unsigned short* __restrict__ idxg,
    const float* __restrict__ W3g,
    const float* __restrict__ g1, const float* __restrict__ b1,
    const float* __restrict__ g2, const float* __restrict__ b2,
    const float* __restrict__ g3, const float* __restrict__ b3,
    float* __restrict__ out)
{
  __shared__ __attribute__((aligned(128))) char lds[LDS_TOTAL];

  const int bidRaw = blockIdx.x;
  const int bn = (bidRaw & 7) * 1024 + (bidRaw >> 3);   // XCD swizzle (bijective)
  const int b = bn >> 11;
  const int n = bn & (N_ - 1);
  const int t = threadIdx.x;
  const int lane = t & 63, w = t >> 6;
  const int l15 = lane & 15, lg = lane >> 4;
  const unsigned swz = (unsigned)((l15 & 7) << 4);
  const float inv = 1.0f / sqrtf(1.0f + 1e-5f);

  // per-thread BN/bias constants
  float gg1[4], bo1[4];
  #pragma unroll
  for (int nt = 0; nt < 4; ++nt) {
    int o = 64 * w + nt * 16 + l15;
    gg1[nt] = g1[o] * inv; bo1[nt] = b1[o];
  }
  float gg2[2], bo2[2];
  #pragma unroll
  for (int nt = 0; nt < 2; ++nt) {
    int p = 32 * w + nt * 16 + l15;
    gg2[nt] = g2[p] * inv; bo2[nt] = b2[p];
  }
  const float g3c = g3[0] * inv, b3c = b3[0];

  auto STAGE = [&](int sl) {
    const char* src; int rounds;
    char* dst = lds + OFF_W + ((sl & 1) << 15);
    if (sl < 5) { src = w1p + (size_t)sl * 32768; rounds = 8; }
    else        { src = w2p + (size_t)(sl - 5) * 16384; rounds = 4; }
    const char* gp = src + t * 16;
    char* lp = dst + ((t >> 6) << 10);
    for (int i = 0; i < rounds; ++i)
      gl_lds16(gp + i * 4096, lp + i * 4096);
  };

  f32x4 acc1[4][4] = {};
  f32x4 acc2[4][2] = {};

  // ---- prologue: stage slice 0, misc, gather h limbs ----
  STAGE(0);
  if (t < 64) ((int*)(lds + OFF_IDX))[t] = (int)idxg[(size_t)bn * 64 + t];
  if (t < 160) {
    float qv = 0.0f;
    if (t < 3) qv = 2.0f * xyz[(size_t)bn * 3 + t];
    else if (t < 131) qv = feat_nc[(size_t)bn * C_ + (t - 3)];
    ((float*)(lds + OFF_Q))[t] = qv;
  }
  if (t < 128) ((float*)(lds + OFF_W3))[t] = W3g[t];
  __syncthreads();

  for (int i = t; i < 64 * 160; i += 256) {
    int s = i / 160, c = i - s * 160;
    int m = ((const int*)(lds + OFF_IDX))[s];
    float p;
    if (c < 3)        p = xyz[((size_t)b * N_ + m) * 3 + c];
    else if (c < 131) p = feat_nc[((size_t)b * N_ + m) * C_ + (c - 3)];
    else              p = 0.0f;
    float q = ((const float*)(lds + OFF_Q))[c];
    float d = p - q;
    float h = (c < 131) ? d * d : 0.0f;
    f16 hi = (f16)h; f16 lo = (f16)(h - (float)hi);
    unsigned byte = ((unsigned)(s * 384 + c * 2)) ^ ((unsigned)((s & 7) << 4));
    *(f16*)(lds + OFF_HHI + byte) = hi;
    *(f16*)(lds + OFF_HLO + byte) = lo;
    if (c < 3)
      *(float*)(lds + OFF_GX + s * 16 + c * 4) = d + xyz[(size_t)bn * 3 + c];
  }
  asm volatile("s_waitcnt vmcnt(0)" ::: "memory");
  __syncthreads();

  // ---- GEMM1: 5 K-slices ----
  for (int kc = 0; kc < 5; ++kc) {
    STAGE(kc + 1);
    {
      const char* wbase = lds + OFF_W + ((kc & 1) << 15);
      f16x8 ah[4], al[4], bh[4], bl[4];
      #pragma unroll
      for (int mt = 0; mt < 4; ++mt) {
        unsigned ba = ((unsigned)((16 * mt + l15) * 384 + kc * 64 + lg * 16)) ^ swz;
        ah[mt] = *(const f16x8*)(lds + OFF_HHI + ba);
        al[mt] = *(const f16x8*)(lds + OFF_HLO + ba);
      }
      #pragma unroll
      for (int nt = 0; nt < 4; ++nt) {
        unsigned bb = ((unsigned)(((64 * w + nt * 16 + l15) << 6) + lg * 16)) ^ swz;
        bh[nt] = *(const f16x8*)(wbase + bb);
        bl[nt] = *(const f16x8*)(wbase + 16384 + bb);
      }
      #pragma unroll
      for (int mt = 0; mt < 4; ++mt)
        #pragma unroll
        for (int nt = 0; nt < 4; ++nt) {
          f32x4 c = acc1[mt][nt];
          c = __builtin_amdgcn_mfma_f32_16x16x32_f16(ah[mt], bh[nt], c, 0, 0, 0);
          c = __builtin_amdgcn_mfma_f32_16x16x32_f16(al[mt], bh[nt], c, 0, 0, 0);
          c = __builtin_amdgcn_mfma_f32_16x16x32_f16(ah[mt], bl[nt], c, 0, 0, 0);
          acc1[mt][nt] = c;
        }
    }
    if (kc == 4) {
      __syncthreads();   // h region dead -> write a1 limbs (overlay)
      #pragma unroll
      for (int mt = 0; mt < 4; ++mt)
        #pragma unroll
        for (int nt = 0; nt < 4; ++nt) {
          int o = 64 * w + nt * 16 + l15;
          #pragma unroll
          for (int r = 0; r < 4; ++r) {
            int s = 16 * mt + 4 * lg + r;
            float a = fmaf(acc1[mt][nt][r], gg1[nt], bo1[nt]);
            a = a > 0.0f ? a : 0.0f;
            f16 hi = (f16)a; f16 lo = (f16)(a - (float)hi);
            unsigned byte = ((unsigned)((s << 9) + o * 2)) ^ ((unsigned)((s & 7) << 4));
            *(f16*)(lds + OFF_A1HI + byte) = hi;
            *(f16*)(lds + OFF_A1LO + byte) = lo;
          }
        }
    }
    asm volatile("s_waitcnt vmcnt(0)" ::: "memory");
    __syncthreads();
  }

  // ---- GEMM2: 8 K-slices ----
  for (int kk = 0; kk < 8; ++kk) {
    if (kk < 7) STAGE(6 + kk);
    {
      const char* wbase = lds + OFF_W + (((5 + kk) & 1) << 15);
      f16x8 ah[4], al[4], bh[2], bl[2];
      #pragma unroll
      for (int mt = 0; mt < 4; ++mt) {
        unsigned ba = ((unsigned)(((16 * mt + l15) << 9) + kk * 64 + lg * 16)) ^ swz;
        ah[mt] = *(const f16x8*)(lds + OFF_A1HI + ba);
        al[mt] = *(const f16x8*)(lds + OFF_A1LO + ba);
      }
      #pragma unroll
      for (int nt = 0; nt < 2; ++nt) {
        unsigned bb = ((unsigned)(((32 * w + nt * 16 + l15) << 6) + lg * 16)) ^ swz;
        bh[nt] = *(const f16x8*)(wbase + bb);
        bl[nt] = *(const f16x8*)(wbase + 8192 + bb);
      }
      #pragma unroll
      for (int mt = 0; mt < 4; ++mt)
        #pragma unroll
        for (int nt = 0; nt < 2; ++nt) {
          f32x4 c = acc2[mt][nt];
          c = __builtin_amdgcn_mfma_f32_16x16x32_f16(ah[mt], bh[nt], c, 0, 0, 0);
          c = __builtin_amdgcn_mfma_f32_16x16x32_f16(al[mt], bh[nt], c, 0, 0, 0);
          c = __builtin_amdgcn_mfma_f32_16x16x32_f16(ah[mt], bl[nt], c, 0, 0, 0);
          acc2[mt][nt] = c;
        }
    }
    asm volatile("s_waitcnt vmcnt(0)" ::: "memory");
    __syncthreads();
  }

  // ---- epilogue2: a2 = relu(bn2(z2)) -> LDS f32 [64][132] ----
  #pragma unroll
  for (int mt = 0; mt < 4; ++mt)
    #pragma unroll
    for (int nt = 0; nt < 2; ++nt) {
      int p = 32 * w + nt * 16 + l15;
      #pragma unroll
      for (int r = 0; r < 4; ++r) {
        int s = 16 * mt + 4 * lg + r;
        float a = fmaf(acc2[mt][nt][r], gg2[nt], bo2[nt]);
        a = a > 0.0f ? a : 0.0f;
        *(float*)(lds + OFF_A2 + s * 528 + p * 4) = a;
      }
    }
  __syncthreads();

  // ---- GEMM3 + weighted mean ----
  {
    int s3 = t >> 2, q3 = t & 3;
    const float* a2r = (const float*)(lds + OFF_A2 + s3 * 528);
    const float* w3r = (const float*)(lds + OFF_W3);
    float z3 = 0.0f;
    #pragma unroll
    for (int i = 0; i < 8; ++i) {
      f32x4 av = *(const f32x4*)(a2r + q3 * 32 + i * 4);
      f32x4 wv = *(const f32x4*)(w3r + q3 * 32 + i * 4);
      z3 = fmaf(av[0], wv[0], z3); z3 = fmaf(av[1], wv[1], z3);
      z3 = fmaf(av[2], wv[2], z3); z3 = fmaf(av[3], wv[3], z3);
    }
    z3 += __shfl_xor(z3, 1);
    z3 += __shfl_xor(z3, 2);
    float wgt = fmaf(g3c, z3, b3c);
    wgt = wgt > 0.0f ? wgt : 0.0f;
    float v0 = 0.f, v1 = 0.f, v2 = 0.f, v3 = 0.f;
    if (q3 == 0) {
      const float* gx = (const float*)(lds + OFF_GX + s3 * 16);
      v0 = gx[0] * wgt; v1 = gx[1] * wgt; v2 = gx[2] * wgt; v3 = wgt;
    }
    #pragma unroll
    for (int off = 4; off < 64; off <<= 1) {
      v0 += __shfl_xor(v0, off); v1 += __shfl_xor(v1, off);
      v2 += __shfl_xor(v2, off); v3 += __shfl_xor(v3, off);
    }
    if (lane == 0) {
      float* red = (float*)(lds + OFF_RED);
      red[w * 4 + 0] = v0; red[w * 4 + 1] = v1;
      red[w * 4 + 2] = v2; red[w * 4 + 3] = v3;
    }
    __syncthreads();
    if (t == 0) {
      const float* red = (const float*)(lds + OFF_RED);
      float n0 = red[0] + red[4] + red[8]  + red[12];
      float n1 = red[1] + red[5] + red[9]  + red[13];
      float n2 = red[2] + red[6] + red[10] + red[14];
      float dd = red[3] + red[7] + red[11] + red[15];
      out[(size_t)(b * 3 + 0) * N_ + n] = n0 / dd;
      out[(size_t)(b * 3 + 1) * N_ + n] = n1 / dd;
      out[(size_t)(b * 3 + 2) * N_ + n] = n2 / dd;
    }
  }
}

extern "C" void kernel_launch(void* const* d_in, const int* in_sizes, int n_in,
                              void* d_out, int out_size, void* d_ws, size_t ws_size,
                              hipStream_t stream) {
  (void)in_sizes; (void)n_in; (void)out_size; (void)ws_size;
  const float* xyz      = (const float*)d_in[0];
  const float* features = (const float*)d_in[1];
  const float* W1 = (const float*)d_in[2];
  const float* W2 = (const float*)d_in[3];
  const float* W3 = (const float*)d_in[4];
  const float* g1 = (const float*)d_in[5];
  const float* g2 = (const float*)d_in[6];
  const float* g3 = (const float*)d_in[7];
  const float* b1 = (const float*)d_in[8];
  const float* b2 = (const float*)d_in[9];
  const float* b3 = (const float*)d_in[10];
  float* out = (float*)d_out;

  char* ws = (char*)d_ws;
  float* feat_nc         = (float*)(ws + WS_FEATNC);
  unsigned short* idx    = (unsigned short*)(ws + WS_IDX);
  f16* W1p               = (f16*)(ws + WS_W1P);
  f16* W2p               = (f16*)(ws + WS_W2P);

  prep_kernel<<<dim3((B_ * C_ * N_) / 256), dim3(256), 0, stream>>>(
      features, W1, W2, feat_nc, W1p, W2p);
  ballquery_kernel<<<dim3(B_ * N_ / 4), dim3(256), 0, stream>>>(xyz, idx);
  mlp_kernel<<<dim3(B_ * N_), dim3(256), 0, stream>>>(
      xyz, feat_nc, (const char*)W1p, (const char*)W2p, idx, W3,
      g1, b1, g2, b2, g3, b3, out);
}

// Round 3
// 332.913 us; speedup vs baseline: 4.5417x; 2.3812x over previous
//
#include <hip/hip_runtime.h>
#include <math.h>

typedef _Float16 f16;
typedef _Float16 f16x8 __attribute__((ext_vector_type(8)));
typedef float f32x4 __attribute__((ext_vector_type(4)));

#define B_  4
#define N_  2048
#define C_  128
#define NS_ 64

// ---- workspace layout (bytes) ----
#define WS_FEATNC 0u          // B*N*C f32 = 4194304
#define WS_IDX    4194304u    // B*N*NS u16 = 1048576
#define WS_W1P    5242880u    // 9 slices * 16384 = 147456
#define WS_W2P    5390336u    // 16 slices * 8192 = 131072

// ---- mlp LDS layout (bytes) ----
#define OFF_REG   0           // h: 9*4096=36864 ; a1 half: 8*4096=32768 (overlay); a2: 64*528=33792 (overlay)
#define REG_SZ    36864
#define OFF_W     36864       // weight dbuf 2*16384
#define OFF_IDX   69632       // 64*4
#define OFF_Q     69888       // 144*4
#define OFF_GX    70464       // 64*16
#define OFF_W3    71488       // 128*4
#define OFF_RED   72000       // 16*4
#define LDS_TOTAL 72064

__device__ __forceinline__ void gl_lds16(const char* gp, char* lp) {
  __builtin_amdgcn_global_load_lds(
      (const __attribute__((address_space(1))) unsigned int*)gp,
      (__attribute__((address_space(3))) unsigned int*)lp, 16, 0, 0);
}

__device__ __forceinline__ unsigned packpair(float v) {
  f16 hi = (f16)v;
  float r = (float)hi;
  f16 lo = (f16)(v - r);
  union { f16 h[2]; unsigned u; } cv;
  cv.h[0] = hi; cv.h[1] = lo;
  return cv.u;
}

__device__ __forceinline__ f16x8 rot16(f16x8 v) {
  union { f16x8 h; unsigned u[4]; } a;
  a.h = v;
  #pragma unroll
  for (int i = 0; i < 4; ++i) a.u[i] = (a.u[i] >> 16) | (a.u[i] << 16);
  return a.h;
}

// ---------------------------------------------------------------------------
// prep: feat (B,C,N)->(B,N,C) f32; W1 -> 9 K-groups (16 c) pair-packed
// swizzled [256 o][64B]; W2 -> 16 o-groups pair-packed swizzled [128 p][64B].
// Images are the exact LDS bytes so mlp stages with linear global_load_lds.
// ---------------------------------------------------------------------------
__global__ __launch_bounds__(256) void prep_kernel(
    const float* __restrict__ feat, const float* __restrict__ W1,
    const float* __restrict__ W2, float* __restrict__ feat_nc,
    char* __restrict__ W1p, char* __restrict__ W2p)
{
  int i = blockIdx.x * 256 + threadIdx.x;
  {
    int n = i & (N_ - 1);
    int bc = i >> 11;
    int c = bc & (C_ - 1);
    int b = bc >> 7;
    feat_nc[(size_t)((b << 11) + n) * C_ + c] = feat[i];
  }
  if (i < 9 * 4096) {          // W1: g[9] x o[256] x cl[16]
    int g = i >> 12; int r = i & 4095; int o = r >> 4; int cl = r & 15;
    int c = g * 16 + cl;
    float wv = (c < 131) ? W1[o * 131 + c] : 0.0f;
    unsigned byte = ((unsigned)(o * 64 + cl * 4)) ^ ((unsigned)(((o >> 1) & 7) << 4));
    *(unsigned*)(W1p + (size_t)g * 16384 + byte) = packpair(wv);
  }
  if (i < 16 * 2048) {         // W2: ko[16] x p[128] x ol[16]
    int ko = i >> 11; int r = i & 2047; int p = r >> 4; int ol = r & 15;
    int o = ko * 16 + ol;
    float wv = W2[p * 256 + o];
    unsigned byte = ((unsigned)(p * 64 + ol * 4)) ^ ((unsigned)(((p >> 1) & 7) << 4));
    *(unsigned*)(W2p + (size_t)ko * 8192 + byte) = packpair(wv);
  }
}

// ---------------------------------------------------------------------------
// ball query (fp64-exact membership), output u16
// ---------------------------------------------------------------------------
__global__ __launch_bounds__(256) void ballquery_kernel(
    const float* __restrict__ xyz, unsigned short* __restrict__ idxout)
{
  __shared__ float  xl[N_ * 3];
  __shared__ double sq[N_];
  __shared__ int    ibuf[4][NS_];

  const int b  = blockIdx.x >> 9;
  const int ng = blockIdx.x & 511;
  const int t  = threadIdx.x;
  const float* xb = xyz + (size_t)b * N_ * 3;

  for (int i = t; i < N_ * 3; i += 256) xl[i] = xb[i];
  __syncthreads();
  for (int i = t; i < N_; i += 256) {
    double x = (double)xl[3*i], y = (double)xl[3*i+1], z = (double)xl[3*i+2];
    sq[i] = x*x + y*y + z*z;
  }
  __syncthreads();

  const int wv = t >> 6, lane = t & 63;
  const int n = ng * 4 + wv;
  const double xn = (double)xl[3*n], yn = (double)xl[3*n+1], zn = (double)xl[3*n+2];
  const double sn = sq[n];

  int cnt = 0;
  for (int mb = 0; mb < N_; mb += 64) {
    int m = mb + lane;
    double dot = xn*(double)xl[3*m] + yn*(double)xl[3*m+1] + zn*(double)xl[3*m+2];
    double d2 = (sn + sq[m]) - 2.0 * dot;
    bool hit = d2 < 0.0625;
    unsigned long long mask = __ballot(hit);
    int pos = __popcll(mask & ((1ULL << lane) - 1ULL));
    int slot = cnt + pos;
    if (hit && slot < NS_) ibuf[wv][slot] = m;
    cnt += (int)__popcll(mask);
    if (cnt >= NS_) break;
  }
  asm volatile("s_waitcnt lgkmcnt(0)" ::: "memory");
  int total = cnt < NS_ ? cnt : NS_;
  int v = ibuf[wv][lane < total ? lane : 0];
  idxout[((size_t)b * N_ + n) * NS_ + lane] = (unsigned short)v;
}

// ---------------------------------------------------------------------------
// MLP via f16 MFMA, pair-packed limbs (K'=2K), rotate-A second MFMA gives the
// full compensated product. One block (4 waves) per (b,n); LDS 72KB ->
// 2 blocks/CU. GEMM1 K'=288 (9 phases), GEMM2 K'=512 (16 phases), a1 K-half
// split (32KB overlaying h). Depth-1 dbuf staging via global_load_lds.
// ---------------------------------------------------------------------------
__global__ __launch_bounds__(256, 2) void mlp_kernel(
    const float* __restrict__ xyz, const float* __restrict__ feat_nc,
    const char* __restrict__ w1p, const char* __restrict__ w2p,
    const unsigned short* __restrict__ idxg,
    const float* __restrict__ W3g,
    const float* __restrict__ g1, const float* __restrict__ b1,
    const float* __restrict__ g2, const float* __restrict__ b2,
    const float* __restrict__ g3, const float* __restrict__ b3,
    float* __restrict__ out)
{
  __shared__ __attribute__((aligned(128))) char lds[LDS_TOTAL];

  const int bidRaw = blockIdx.x;
  const int bn = ((bidRaw & 7) << 10) + (bidRaw >> 3);   // XCD swizzle (bijective)
  const int b = bn >> 11;
  const int n = bn & (N_ - 1);
  const int t = threadIdx.x;
  const int w = t >> 6, lane = t & 63;
  const int l15 = lane & 15, lg = lane >> 4;
  // lane-constant fragment base: rows are (16*k + l15), so XOR mask is lane-const
  const unsigned labase = ((unsigned)(l15 * 64 + lg * 16)) ^ ((unsigned)(((l15 >> 1) & 7) << 4));
  const float inv = 1.0f / sqrtf(1.0f + 1e-5f);

  float gg1v[4], bo1v[4];
  #pragma unroll
  for (int nt = 0; nt < 4; ++nt) {
    int o = (nt >> 1) * 128 + 32 * w + (nt & 1) * 16 + l15;
    gg1v[nt] = g1[o] * inv; bo1v[nt] = b1[o];
  }
  float gg2v[2], bo2v[2];
  #pragma unroll
  for (int nt = 0; nt < 2; ++nt) {
    int p = 32 * w + nt * 16 + l15;
    gg2v[nt] = g2[p] * inv; bo2v[nt] = b2[p];
  }
  const float g3c = g3[0] * inv, b3c = b3[0];

  auto STAGE_W1 = [&](int g, int buf) {
    const char* gp = w1p + (size_t)g * 16384 + t * 16;
    char* lp = lds + OFF_W + (buf << 14) + (w << 10);
    #pragma unroll
    for (int i2 = 0; i2 < 4; ++i2) gl_lds16(gp + i2 * 4096, lp + i2 * 4096);
  };
  auto STAGE_W2 = [&](int ko, int buf) {
    const char* gp = w2p + (size_t)ko * 8192 + t * 16;
    char* lp = lds + OFF_W + (buf << 14) + (w << 10);
    gl_lds16(gp, lp);
    gl_lds16(gp + 4096, lp + 4096);
  };

  f32x4 acc1[4][4] = {};
  f32x4 acc2[4][2] = {};

  // ---- prologue ----
  STAGE_W1(0, 0);
  if (t < 64) ((int*)(lds + OFF_IDX))[t] = (int)idxg[(size_t)bn * 64 + t];
  if (t < 144) {
    float qv = 0.0f;
    if (t < 3) qv = 2.0f * xyz[(size_t)bn * 3 + t];
    else if (t < 131) qv = feat_nc[(size_t)bn * C_ + (t - 3)];
    ((float*)(lds + OFF_Q))[t] = qv;
  }
  if (t < 128) ((float*)(lds + OFF_W3))[t] = W3g[t];
  __syncthreads();

  const int* idxl = (const int*)(lds + OFF_IDX);
  const float* ql = (const float*)(lds + OFF_Q);

  // gather h: c<3 (xyz) + gx
  {
    int s = t & 63, c = t >> 6;
    if (c < 3) {
      int m = idxl[s];
      float p = xyz[((size_t)b * N_ + m) * 3 + c];
      float d = p - ql[c];
      unsigned swz = (unsigned)(((s >> 1) & 7) << 4);
      unsigned byte = ((unsigned)(s * 64 + c * 4)) ^ swz;
      *(unsigned*)(lds + OFF_REG + byte) = packpair(d * d);
      *(float*)(lds + OFF_GX + s * 16 + c * 4) = p - xyz[(size_t)bn * 3 + c];
    }
  }
  // gather h: c = 3..130 via float4 (j = c-3 aligned)
  for (int i = t; i < 64 * 32; i += 256) {
    int s = i >> 5, q4 = i & 31;
    int m = idxl[s];
    f32x4 f = *(const f32x4*)(feat_nc + ((size_t)b * N_ + m) * C_ + q4 * 4);
    unsigned swz = (unsigned)(((s >> 1) & 7) << 4);
    #pragma unroll
    for (int e = 0; e < 4; ++e) {
      int c = q4 * 4 + 3 + e;
      float d = f[e] - ql[c];
      unsigned byte = ((unsigned)((c >> 4) * 4096) )
                    + (((unsigned)(s * 64 + (c & 15) * 4)) ^ swz);
      *(unsigned*)(lds + OFF_REG + byte) = packpair(d * d);
    }
  }
  // gather h: c = 128..143 (128..130 real, rest zero; 128..130 benign rewrite)
  for (int i = t; i < 64 * 16; i += 256) {
    int s = i >> 4, cl = i & 15;
    int c = 128 + cl;
    float h = 0.0f;
    if (c < 131) {
      int m = idxl[s];
      float f = feat_nc[((size_t)b * N_ + m) * C_ + (c - 3)];
      float d = f - ql[c];
      h = d * d;
    }
    unsigned swz = (unsigned)(((s >> 1) & 7) << 4);
    unsigned byte = 8u * 4096u + (((unsigned)(s * 64 + cl * 4)) ^ swz);
    *(unsigned*)(lds + OFF_REG + byte) = packpair(h);
  }
  __syncthreads();

  // ---- GEMM1: 9 phases ----
  for (int g = 0; g < 9; ++g) {
    if (g < 8) STAGE_W1(g + 1, (g + 1) & 1);
    else       STAGE_W2(0, 1);                      // j=9
    const char* wb = lds + OFF_W + ((g & 1) << 14);
    const char* hb = lds + OFF_REG + g * 4096;
    f16x8 af[4], ar[4], bf[4];
    #pragma unroll
    for (int mt = 0; mt < 4; ++mt) {
      af[mt] = *(const f16x8*)(hb + mt * 1024 + labase);
      ar[mt] = rot16(af[mt]);
    }
    #pragma unroll
    for (int nt = 0; nt < 4; ++nt) {
      int ob = (nt >> 1) * 128 + 32 * w + (nt & 1) * 16;
      bf[nt] = *(const f16x8*)(wb + ob * 64 + labase);
    }
    __builtin_amdgcn_s_setprio(1);
    #pragma unroll
    for (int mt = 0; mt < 4; ++mt)
      #pragma unroll
      for (int nt = 0; nt < 4; ++nt) {
        f32x4 c = acc1[mt][nt];
        c = __builtin_amdgcn_mfma_f32_16x16x32_f16(af[mt], bf[nt], c, 0, 0, 0);
        c = __builtin_amdgcn_mfma_f32_16x16x32_f16(ar[mt], bf[nt], c, 0, 0, 0);
        acc1[mt][nt] = c;
      }
    __builtin_amdgcn_s_setprio(0);
    __syncthreads();
  }

  // ---- epilogue1 half0: a1 for o<128 -> region groups 0..7 ----
  auto EPI1 = [&](int hf) {
    #pragma unroll
    for (int mt = 0; mt < 4; ++mt)
      #pragma unroll
      for (int nt2 = 0; nt2 < 2; ++nt2) {
        int nt = hf * 2 + nt2;
        int o = hf * 128 + 32 * w + nt2 * 16 + l15;
        int g2 = (o >> 4) & 7;
        #pragma unroll
        for (int r = 0; r < 4; ++r) {
          int s = mt * 16 + lg * 4 + r;
          float a = fmaf(acc1[mt][nt][r], gg1v[nt], bo1v[nt]);
          a = a > 0.0f ? a : 0.0f;
          unsigned byte = (unsigned)(g2 * 4096)
                        + (((unsigned)(s * 64 + (o & 15) * 4)) ^ ((unsigned)(((s >> 1) & 7) << 4)));
          *(unsigned*)(lds + OFF_REG + byte) = packpair(a);
        }
      }
  };
  EPI1(0);
  __syncthreads();

  // ---- GEMM2: 16 phases, K-half split ----
  for (int ko = 0; ko < 16; ++ko) {
    int j = 9 + ko;
    if (ko < 15) STAGE_W2(ko + 1, (j + 1) & 1);
    const char* wb = lds + OFF_W + ((j & 1) << 14);
    const char* ab = lds + OFF_REG + (ko & 7) * 4096;
    f16x8 af[4], ar[4], bf[2];
    #pragma unroll
    for (int mt = 0; mt < 4; ++mt) {
      af[mt] = *(const f16x8*)(ab + mt * 1024 + labase);
      ar[mt] = rot16(af[mt]);
    }
    #pragma unroll
    for (int nt2 = 0; nt2 < 2; ++nt2) {
      int pb = 32 * w + nt2 * 16;
      bf[nt2] = *(const f16x8*)(wb + pb * 64 + labase);
    }
    __builtin_amdgcn_s_setprio(1);
    #pragma unroll
    for (int mt = 0; mt < 4; ++mt)
      #pragma unroll
      for (int nt2 = 0; nt2 < 2; ++nt2) {
        f32x4 c = acc2[mt][nt2];
        c = __builtin_amdgcn_mfma_f32_16x16x32_f16(af[mt], bf[nt2], c, 0, 0, 0);
        c = __builtin_amdgcn_mfma_f32_16x16x32_f16(ar[mt], bf[nt2], c, 0, 0, 0);
        acc2[mt][nt2] = c;
      }
    __builtin_amdgcn_s_setprio(0);
    if (ko == 7) {         // a1 half0 fully consumed -> write half1
      __syncthreads();
      EPI1(1);
    }
    __syncthreads();
  }

  // ---- epilogue2: a2 = relu(bn2(z2)) -> f32 [64][132] (stride 528B) ----
  #pragma unroll
  for (int mt = 0; mt < 4; ++mt)
    #pragma unroll
    for (int nt2 = 0; nt2 < 2; ++nt2) {
      int p = 32 * w + nt2 * 16 + l15;
      #pragma unroll
      for (int r = 0; r < 4; ++r) {
        int s = mt * 16 + lg * 4 + r;
        float a = fmaf(acc2[mt][nt2][r], gg2v[nt2], bo2v[nt2]);
        a = a > 0.0f ? a : 0.0f;
        *(float*)(lds + OFF_REG + s * 528 + p * 4) = a;
      }
    }
  __syncthreads();

  // ---- GEMM3 + weighted mean ----
  {
    int s3 = t >> 2, q3 = t & 3;
    const float* a2r = (const float*)(lds + OFF_REG) + s3 * 132;
    const float* w3r = (const float*)(lds + OFF_W3);
    float z3 = 0.0f;
    #pragma unroll
    for (int i = 0; i < 8; ++i) {
      f32x4 av = *(const f32x4*)(a2r + q3 * 32 + i * 4);
      f32x4 wv = *(const f32x4*)(w3r + q3 * 32 + i * 4);
      z3 = fmaf(av[0], wv[0], z3); z3 = fmaf(av[1], wv[1], z3);
      z3 = fmaf(av[2], wv[2], z3); z3 = fmaf(av[3], wv[3], z3);
    }
    z3 += __shfl_xor(z3, 1);
    z3 += __shfl_xor(z3, 2);
    float wgt = fmaf(g3c, z3, b3c);
    wgt = wgt > 0.0f ? wgt : 0.0f;
    float v0 = 0.f, v1 = 0.f, v2 = 0.f, v3 = 0.f;
    if (q3 == 0) {
      const float* gx = (const float*)(lds + OFF_GX + s3 * 16);
      v0 = gx[0] * wgt; v1 = gx[1] * wgt; v2 = gx[2] * wgt; v3 = wgt;
    }
    #pragma unroll
    for (int off = 4; off < 64; off <<= 1) {
      v0 += __shfl_xor(v0, off); v1 += __shfl_xor(v1, off);
      v2 += __shfl_xor(v2, off); v3 += __shfl_xor(v3, off);
    }
    if (lane == 0) {
      float* red = (float*)(lds + OFF_RED);
      red[w * 4 + 0] = v0; red[w * 4 + 1] = v1;
      red[w * 4 + 2] = v2; red[w * 4 + 3] = v3;
    }
    __syncthreads();
    if (t == 0) {
      const float* red = (const float*)(lds + OFF_RED);
      float n0 = red[0] + red[4] + red[8]  + red[12];
      float n1 = red[1] + red[5] + red[9]  + red[13];
      float n2 = red[2] + red[6] + red[10] + red[14];
      float dd = red[3] + red[7] + red[11] + red[15];
      out[(size_t)(b * 3 + 0) * N_ + n] = n0 / dd;
      out[(size_t)(b * 3 + 1) * N_ + n] = n1 / dd;
      out[(size_t)(b * 3 + 2) * N_ + n] = n2 / dd;
    }
  }
}

extern "C" void kernel_launch(void* const* d_in, const int* in_sizes, int n_in,
                              void* d_out, int out_size, void* d_ws, size_t ws_size,
                              hipStream_t stream) {
  (void)in_sizes; (void)n_in; (void)out_size; (void)ws_size;
  const float* xyz      = (const float*)d_in[0];
  const float* features = (const float*)d_in[1];
  const float* W1 = (const float*)d_in[2];
  const float* W2 = (const float*)d_in[3];
  const float* W3 = (const float*)d_in[4];
  const float* g1 = (const float*)d_in[5];
  const float* g2 = (const float*)d_in[6];
  const float* g3 = (const float*)d_in[7];
  const float* b1 = (const float*)d_in[8];
  const float* b2 = (const float*)d_in[9];
  const float* b3 = (const float*)d_in[10];
  float* out = (float*)d_out;

  char* ws = (char*)d_ws;
  float* feat_nc      = (float*)(ws + WS_FEATNC);
  unsigned short* idx = (unsigned short*)(ws + WS_IDX);
  char* W1p           = ws + WS_W1P;
  char* W2p           = ws + WS_W2P;

  prep_kernel<<<dim3((B_ * C_ * N_) / 256), dim3(256), 0, stream>>>(
      features, W1, W2, feat_nc, W1p, W2p);
  ballquery_kernel<<<dim3(B_ * N_ / 4), dim3(256), 0, stream>>>(xyz, idx);
  mlp_kernel<<<dim3(B_ * N_), dim3(256), 0, stream>>>(
      xyz, feat_nc, W1p, W2p, idx, W3, g1, b1, g2, b2, g3, b3, out);
}

// Round 4
// 296.041 us; speedup vs baseline: 5.1073x; 1.1246x over previous
//
#include <hip/hip_runtime.h>
#include <math.h>

typedef _Float16 f16;
typedef _Float16 f16x8 __attribute__((ext_vector_type(8)));
typedef float f32x4 __attribute__((ext_vector_type(4)));

#define B_  4
#define N_  2048
#define C_  128
#define NS_ 64

// ---- workspace layout (bytes) ----
#define WS_FEATNC 0u          // B*N*C f32 = 4194304
#define WS_IDX    4194304u    // B*N*NS u16 = 1048576
#define WS_W1P    5242880u    // 16 slices * 8192 = 131072
#define WS_W2P    5373952u    // 16 slices * 8192 = 131072

// ---- mlp LDS layout (bytes), total 54272 -> 3 blocks/CU ----
#define OFF_H   0             // h 8 groups x 4096 = 32768; a1 halves overlay; a2 (33792) overlays H+W
#define OFF_W   32768         // weight dbuf 2 x 8192
#define OFF_W1X 49152         // [3][256] f32 = 3072 (W1 xyz cols)
#define OFF_GX  52224         // [64][3] f32 = 768
#define OFF_QF  52992         // [128] f32 = 512
#define OFF_IDX 53504         // 256 (RED overlays after gather)
#define OFF_RED 53504
#define OFF_W3  53760         // 512
#define LDS_TOTAL 54272

// K-slot permutation within a 16-group (consistent across h, a1, W1, W2)
#define SLOT(x) ((((x) & 3) << 2) | (((x) >> 2) & 3))

__device__ __forceinline__ void gl_lds16(const char* gp, char* lp) {
  __builtin_amdgcn_global_load_lds(
      (const __attribute__((address_space(1))) unsigned int*)gp,
      (__attribute__((address_space(3))) unsigned int*)lp, 16, 0, 0);
}

__device__ __forceinline__ unsigned packpair(float v) {
  f16 hi = (f16)v;
  float r = (float)hi;
  f16 lo = (f16)(v - r);
  union { f16 h[2]; unsigned u; } cv;
  cv.h[0] = hi; cv.h[1] = lo;
  return cv.u;
}

__device__ __forceinline__ f16x8 rot16(f16x8 v) {
  union { f16x8 h; unsigned u[4]; } a;
  a.h = v;
  #pragma unroll
  for (int i = 0; i < 4; ++i) a.u[i] = (a.u[i] >> 16) | (a.u[i] << 16);
  return a.h;
}

// ---------------------------------------------------------------------------
// prep: feat (B,C,N)->(B,N,C) f32; W1 feature-cols -> 16 slices (g,oh)
// [128 o'][16 slot] pair-packed swizzled; W2 -> 16 o-slices [128 p][16 slot].
// Images are exact LDS bytes: mlp stages them with linear global_load_lds.
// ---------------------------------------------------------------------------
__global__ __launch_bounds__(256) void prep_kernel(
    const float* __restrict__ feat, const float* __restrict__ W1,
    const float* __restrict__ W2, float* __restrict__ feat_nc,
    char* __restrict__ W1p, char* __restrict__ W2p)
{
  int i = blockIdx.x * 256 + threadIdx.x;
  {
    int n = i & (N_ - 1);
    int bc = i >> 11;
    int c = bc & (C_ - 1);
    int b = bc >> 7;
    feat_nc[(size_t)((b << 11) + n) * C_ + c] = feat[i];
  }
  if (i < 16 * 2048) {   // W1: sl = g*2+oh; [o' 0..127][cl 0..15]; c = 3 + g*16+cl
    int sl = i >> 11; int r = i & 2047; int op = r >> 4; int cl = r & 15;
    int g = sl >> 1, oh = sl & 1;
    int o = oh * 128 + op;
    float wv = W1[o * 131 + 3 + g * 16 + cl];
    unsigned byte = ((unsigned)(op * 64 + SLOT(cl) * 4)) ^ ((unsigned)(((op >> 1) & 7) << 4));
    *(unsigned*)(W1p + (size_t)sl * 8192 + byte) = packpair(wv);
  }
  if (i < 16 * 2048) {   // W2: ko slices over o; [p 0..127][ol 0..15]
    int ko = i >> 11; int r = i & 2047; int p = r >> 4; int ol = r & 15;
    int o = ko * 16 + ol;
    float wv = W2[p * 256 + o];
    unsigned byte = ((unsigned)(p * 64 + SLOT(ol) * 4)) ^ ((unsigned)(((p >> 1) & 7) << 4));
    *(unsigned*)(W2p + (size_t)ko * 8192 + byte) = packpair(wv);
  }
}

// ---------------------------------------------------------------------------
// ball query (fp64-exact membership), output u16
// ---------------------------------------------------------------------------
__global__ __launch_bounds__(256) void ballquery_kernel(
    const float* __restrict__ xyz, unsigned short* __restrict__ idxout)
{
  __shared__ float  xl[N_ * 3];
  __shared__ double sq[N_];
  __shared__ int    ibuf[4][NS_];

  const int b  = blockIdx.x >> 9;
  const int ng = blockIdx.x & 511;
  const int t  = threadIdx.x;
  const float* xb = xyz + (size_t)b * N_ * 3;

  for (int i = t; i < N_ * 3; i += 256) xl[i] = xb[i];
  __syncthreads();
  for (int i = t; i < N_; i += 256) {
    double x = (double)xl[3*i], y = (double)xl[3*i+1], z = (double)xl[3*i+2];
    sq[i] = x*x + y*y + z*z;
  }
  __syncthreads();

  const int wv = t >> 6, lane = t & 63;
  const int n = ng * 4 + wv;
  const double xn = (double)xl[3*n], yn = (double)xl[3*n+1], zn = (double)xl[3*n+2];
  const double sn = sq[n];

  int cnt = 0;
  for (int mb = 0; mb < N_; mb += 64) {
    int m = mb + lane;
    double dot = xn*(double)xl[3*m] + yn*(double)xl[3*m+1] + zn*(double)xl[3*m+2];
    double d2 = (sn + sq[m]) - 2.0 * dot;
    bool hit = d2 < 0.0625;
    unsigned long long mask = __ballot(hit);
    int pos = __popcll(mask & ((1ULL << lane) - 1ULL));
    int slot = cnt + pos;
    if (hit && slot < NS_) ibuf[wv][slot] = m;
    cnt += (int)__popcll(mask);
    if (cnt >= NS_) break;
  }
  asm volatile("s_waitcnt lgkmcnt(0)" ::: "memory");
  int total = cnt < NS_ ? cnt : NS_;
  int v = ibuf[wv][lane < total ? lane : 0];
  idxout[((size_t)b * N_ + n) * NS_ + lane] = (unsigned short)v;
}

// ---------------------------------------------------------------------------
// MLP: f16 MFMA pair-packed limbs; xyz channels on VALU (acc1 init);
// 54272B LDS -> 3 blocks/CU. GEMM1: 16 phases (8 K-groups x 2 o-halves);
// GEMM2: 16 phases, a1 K-half split. Depth-1 dbuf via global_load_lds.
// ---------------------------------------------------------------------------
__global__ __launch_bounds__(256, 3) void mlp_kernel(
    const float* __restrict__ xyz, const float* __restrict__ feat_nc,
    const char* __restrict__ w1p, const char* __restrict__ w2p,
    const unsigned short* __restrict__ idxg,
    const float* __restrict__ W1g, const float* __restrict__ W3g,
    const float* __restrict__ g1, const float* __restrict__ b1,
    const float* __restrict__ g2, const float* __restrict__ b2,
    const float* __restrict__ g3, const float* __restrict__ b3,
    float* __restrict__ out)
{
  __shared__ __attribute__((aligned(128))) char lds[LDS_TOTAL];

  const int bidRaw = blockIdx.x;
  const int bn = ((bidRaw & 7) << 10) + (bidRaw >> 3);   // XCD swizzle (bijective)
  const int b = bn >> 11;
  const int n = bn & (N_ - 1);
  const int t = threadIdx.x;
  const int w = t >> 6, lane = t & 63;
  const int l15 = lane & 15, lg = lane >> 4;
  const unsigned labase = ((unsigned)(l15 * 64 + lg * 16)) ^ ((unsigned)(((l15 >> 1) & 7) << 4));
  const float inv = 1.0f / sqrtf(1.0f + 1e-5f);

  float gg1v[4], bo1v[4];
  #pragma unroll
  for (int nt = 0; nt < 4; ++nt) {
    int o = (nt >> 1) * 128 + 32 * w + (nt & 1) * 16 + l15;
    gg1v[nt] = g1[o] * inv; bo1v[nt] = b1[o];
  }
  float gg2v[2], bo2v[2];
  #pragma unroll
  for (int nt = 0; nt < 2; ++nt) {
    int p = 32 * w + nt * 16 + l15;
    gg2v[nt] = g2[p] * inv; bo2v[nt] = b2[p];
  }
  const float g3c = g3[0] * inv, b3c = b3[0];
  const float xn0 = xyz[(size_t)bn*3+0], xn1 = xyz[(size_t)bn*3+1], xn2 = xyz[(size_t)bn*3+2];

  auto STAGE = [&](int sl) {
    const char* gp = (sl < 16 ? w1p + (size_t)sl * 8192
                              : w2p + (size_t)(sl - 16) * 8192) + t * 16;
    char* lp = lds + OFF_W + ((sl & 1) << 13) + (w << 10);
    gl_lds16(gp, lp);
    gl_lds16(gp + 4096, lp + 4096);
  };

  f32x4 acc1[4][4];
  f32x4 acc2[4][2] = {};

  // ---- prologue ----
  STAGE(0);
  if (t < 64) ((int*)(lds + OFF_IDX))[t] = (int)idxg[(size_t)bn * 64 + t];
  if (t < 128) ((float*)(lds + OFF_QF))[t] = feat_nc[(size_t)bn * C_ + t];
  if (t < 128) ((float*)(lds + OFF_W3))[t] = W3g[t];
  {
    float* w1x = (float*)(lds + OFF_W1X);
    #pragma unroll
    for (int c = 0; c < 3; ++c) w1x[c * 256 + t] = W1g[t * 131 + c];
  }
  __syncthreads();

  const int* idxl = (const int*)(lds + OFF_IDX);
  const float* qf = (const float*)(lds + OFF_QF);

  // gather features -> h pair-packed (conflict-free via SLOT + group-XOR)
  #pragma unroll
  for (int k = 0; k < 8; ++k) {
    int i = t + k * 256;
    int s = i >> 5, q4 = i & 31;
    int m = idxl[s];
    f32x4 f = *(const f32x4*)(feat_nc + ((size_t)b * N_ + m) * C_ + q4 * 4);
    unsigned sw = ((unsigned)((s >> 1) & 7)) << 4;
    #pragma unroll
    for (int e = 0; e < 4; ++e) {
      int j = q4 * 4 + e;
      float d = f[e] - qf[j];
      int g = j >> 4;
      unsigned byte = (unsigned)(g * 4096)
        + ((((unsigned)(s * 64 + SLOT(j & 15) * 4)) ^ sw ^ ((unsigned)((g & 7) << 4))));
      *(unsigned*)(lds + OFF_H + byte) = packpair(d * d);
    }
  }
  // gather xyz -> GX (relative coords, also feeds VALU z1 contribution)
  if (t < 192) {
    int s = t & 63, c = t >> 6;
    int m = idxl[s];
    float p = xyz[((size_t)b * N_ + m) * 3 + c];
    float xnc = (c == 0) ? xn0 : (c == 1 ? xn1 : xn2);
    ((float*)(lds + OFF_GX))[s * 3 + c] = p - xnc;
  }
  asm volatile("s_waitcnt vmcnt(0)" ::: "memory");
  __syncthreads();

  // ---- xyz-channel contribution: acc1 init on VALU ----
  {
    const float* w1x = (const float*)(lds + OFF_W1X);
    const float* gx = (const float*)(lds + OFF_GX);
    float wx[4][3];
    #pragma unroll
    for (int nt = 0; nt < 4; ++nt) {
      int o = (nt >> 1) * 128 + 32 * w + (nt & 1) * 16 + l15;
      #pragma unroll
      for (int c = 0; c < 3; ++c) wx[nt][c] = w1x[c * 256 + o];
    }
    #pragma unroll
    for (int mt = 0; mt < 4; ++mt)
      #pragma unroll
      for (int r = 0; r < 4; ++r) {
        int s = mt * 16 + lg * 4 + r;
        float d0 = gx[s * 3 + 0] - xn0;
        float d1 = gx[s * 3 + 1] - xn1;
        float d2 = gx[s * 3 + 2] - xn2;
        d0 *= d0; d1 *= d1; d2 *= d2;
        #pragma unroll
        for (int nt = 0; nt < 4; ++nt)
          acc1[mt][nt][r] = fmaf(wx[nt][0], d0, fmaf(wx[nt][1], d1, wx[nt][2] * d2));
      }
  }

  // ---- GEMM1: 16 phases (g 0..7 x oh 0..1) ----
  f16x8 af[4], ar[4];
  #pragma unroll
  for (int p = 0; p < 16; ++p) {
    const int g = p >> 1, oh = p & 1;
    STAGE(p + 1);
    if (oh == 0) {
      const char* hb = lds + OFF_H + g * 4096;
      const unsigned gx4 = ((unsigned)(g & 7)) << 4;
      #pragma unroll
      for (int mt = 0; mt < 4; ++mt) {
        af[mt] = *(const f16x8*)(hb + mt * 1024 + (labase ^ gx4));
        ar[mt] = rot16(af[mt]);
      }
    }
    const char* wb = lds + OFF_W + ((p & 1) << 13);
    f16x8 bf0 = *(const f16x8*)(wb + (32 * w) * 64 + labase);
    f16x8 bf1 = *(const f16x8*)(wb + (32 * w + 16) * 64 + labase);
    __builtin_amdgcn_s_setprio(1);
    #pragma unroll
    for (int mt = 0; mt < 4; ++mt) {
      f32x4 c0 = acc1[mt][oh * 2 + 0];
      c0 = __builtin_amdgcn_mfma_f32_16x16x32_f16(af[mt], bf0, c0, 0, 0, 0);
      c0 = __builtin_amdgcn_mfma_f32_16x16x32_f16(ar[mt], bf0, c0, 0, 0, 0);
      acc1[mt][oh * 2 + 0] = c0;
      f32x4 c1 = acc1[mt][oh * 2 + 1];
      c1 = __builtin_amdgcn_mfma_f32_16x16x32_f16(af[mt], bf1, c1, 0, 0, 0);
      c1 = __builtin_amdgcn_mfma_f32_16x16x32_f16(ar[mt], bf1, c1, 0, 0, 0);
      acc1[mt][oh * 2 + 1] = c1;
    }
    __builtin_amdgcn_s_setprio(0);
    asm volatile("s_waitcnt vmcnt(0)" ::: "memory");
    __syncthreads();
  }

  // ---- epilogue1: a1 half -> h region (pair-packed, swizzled) ----
  auto EPI1 = [&](int hf) {
    const unsigned slotl = (unsigned)SLOT(l15);
    #pragma unroll
    for (int mt = 0; mt < 4; ++mt)
      #pragma unroll
      for (int nt2 = 0; nt2 < 2; ++nt2) {
        const int nt = hf * 2 + nt2;
        const int ga = 2 * w + nt2;
        #pragma unroll
        for (int r = 0; r < 4; ++r) {
          int s = mt * 16 + lg * 4 + r;
          float a = fmaf(acc1[mt][nt][r], gg1v[nt], bo1v[nt]);
          a = a > 0.0f ? a : 0.0f;
          unsigned byte = (unsigned)(ga * 4096)
            + ((((unsigned)(s * 64) + slotl * 4)) ^ ((unsigned)(((s >> 1) & 7) << 4))
               ^ ((unsigned)((ga & 7) << 4)));
          *(unsigned*)(lds + OFF_H + byte) = packpair(a);
        }
      }
  };
  EPI1(0);
  __syncthreads();

  // ---- GEMM2: 16 phases, a1 half-split at ko==8 ----
  #pragma unroll
  for (int ko = 0; ko < 16; ++ko) {
    if (ko < 15) STAGE(17 + ko);
    const char* ab = lds + OFF_H + (ko & 7) * 4096;
    const unsigned gx4 = ((unsigned)(ko & 7)) << 4;
    f16x8 a2f[4], a2r[4];
    #pragma unroll
    for (int mt = 0; mt < 4; ++mt) {
      a2f[mt] = *(const f16x8*)(ab + mt * 1024 + (labase ^ gx4));
      a2r[mt] = rot16(a2f[mt]);
    }
    const char* wb = lds + OFF_W + ((ko & 1) << 13);
    f16x8 bf0 = *(const f16x8*)(wb + (32 * w) * 64 + labase);
    f16x8 bf1 = *(const f16x8*)(wb + (32 * w + 16) * 64 + labase);
    __builtin_amdgcn_s_setprio(1);
    #pragma unroll
    for (int mt = 0; mt < 4; ++mt) {
      f32x4 c0 = acc2[mt][0];
      c0 = __builtin_amdgcn_mfma_f32_16x16x32_f16(a2f[mt], bf0, c0, 0, 0, 0);
      c0 = __builtin_amdgcn_mfma_f32_16x16x32_f16(a2r[mt], bf0, c0, 0, 0, 0);
      acc2[mt][0] = c0;
      f32x4 c1 = acc2[mt][1];
      c1 = __builtin_amdgcn_mfma_f32_16x16x32_f16(a2f[mt], bf1, c1, 0, 0, 0);
      c1 = __builtin_amdgcn_mfma_f32_16x16x32_f16(a2r[mt], bf1, c1, 0, 0, 0);
      acc2[mt][1] = c1;
    }
    __builtin_amdgcn_s_setprio(0);
    asm volatile("s_waitcnt vmcnt(0)" ::: "memory");
    __syncthreads();
    if (ko == 7) {       // a1 half0 consumed -> write half1
      EPI1(1);
      __syncthreads();
    }
  }

  // ---- epilogue2: a2 = relu(bn2(z2)) f32, rows stride 528B (overlays H+W) ----
  #pragma unroll
  for (int mt = 0; mt < 4; ++mt)
    #pragma unroll
    for (int nt2 = 0; nt2 < 2; ++nt2) {
      int p2 = 32 * w + nt2 * 16 + l15;
      #pragma unroll
      for (int r = 0; r < 4; ++r) {
        int s = mt * 16 + lg * 4 + r;
        float a = fmaf(acc2[mt][nt2][r], gg2v[nt2], bo2v[nt2]);
        a = a > 0.0f ? a : 0.0f;
        *(float*)(lds + s * 528 + p2 * 4) = a;
      }
    }
  __syncthreads();

  // ---- GEMM3 + weighted mean ----
  {
    int s3 = t >> 2, q3 = t & 3;
    const float* a2row = (const float*)lds + s3 * 132;
    const float* w3r = (const float*)(lds + OFF_W3);
    float z3 = 0.0f;
    #pragma unroll
    for (int i = 0; i < 8; ++i) {
      f32x4 av = *(const f32x4*)(a2row + q3 * 32 + i * 4);
      f32x4 wv = *(const f32x4*)(w3r + q3 * 32 + i * 4);
      z3 = fmaf(av[0], wv[0], z3); z3 = fmaf(av[1], wv[1], z3);
      z3 = fmaf(av[2], wv[2], z3); z3 = fmaf(av[3], wv[3], z3);
    }
    z3 += __shfl_xor(z3, 1);
    z3 += __shfl_xor(z3, 2);
    float wgt = fmaf(g3c, z3, b3c);
    wgt = wgt > 0.0f ? wgt : 0.0f;
    float v0 = 0.f, v1 = 0.f, v2 = 0.f, v3 = 0.f;
    if (q3 == 0) {
      const float* gx = (const float*)(lds + OFF_GX) + s3 * 3;
      v0 = gx[0] * wgt; v1 = gx[1] * wgt; v2 = gx[2] * wgt; v3 = wgt;
    }
    #pragma unroll
    for (int off = 4; off < 64; off <<= 1) {
      v0 += __shfl_xor(v0, off); v1 += __shfl_xor(v1, off);
      v2 += __shfl_xor(v2, off); v3 += __shfl_xor(v3, off);
    }
    if (lane == 0) {
      float* red = (float*)(lds + OFF_RED);
      red[w * 4 + 0] = v0; red[w * 4 + 1] = v1;
      red[w * 4 + 2] = v2; red[w * 4 + 3] = v3;
    }
    __syncthreads();
    if (t == 0) {
      const float* red = (const float*)(lds + OFF_RED);
      float n0 = red[0] + red[4] + red[8]  + red[12];
      float n1 = red[1] + red[5] + red[9]  + red[13];
      float n2 = red[2] + red[6] + red[10] + red[14];
      float dd = red[3] + red[7] + red[11] + red[15];
      out[(size_t)(b * 3 + 0) * N_ + n] = n0 / dd;
      out[(size_t)(b * 3 + 1) * N_ + n] = n1 / dd;
      out[(size_t)(b * 3 + 2) * N_ + n] = n2 / dd;
    }
  }
}

extern "C" void kernel_launch(void* const* d_in, const int* in_sizes, int n_in,
                              void* d_out, int out_size, void* d_ws, size_t ws_size,
                              hipStream_t stream) {
  (void)in_sizes; (void)n_in; (void)out_size; (void)ws_size;
  const float* xyz      = (const float*)d_in[0];
  const float* features = (const float*)d_in[1];
  const float* W1 = (const float*)d_in[2];
  const float* W2 = (const float*)d_in[3];
  const float* W3 = (const float*)d_in[4];
  const float* g1 = (const float*)d_in[5];
  const float* g2 = (const float*)d_in[6];
  const float* g3 = (const float*)d_in[7];
  const float* b1 = (const float*)d_in[8];
  const float* b2 = (const float*)d_in[9];
  const float* b3 = (const float*)d_in[10];
  float* out = (float*)d_out;

  char* ws = (char*)d_ws;
  float* feat_nc      = (float*)(ws + WS_FEATNC);
  unsigned short* idx = (unsigned short*)(ws + WS_IDX);
  char* W1p           = ws + WS_W1P;
  char* W2p           = ws + WS_W2P;

  prep_kernel<<<dim3((B_ * C_ * N_) / 256), dim3(256), 0, stream>>>(
      features, W1, W2, feat_nc, W1p, W2p);
  ballquery_kernel<<<dim3(B_ * N_ / 4), dim3(256), 0, stream>>>(xyz, idx);
  mlp_kernel<<<dim3(B_ * N_), dim3(256), 0, stream>>>(
      xyz, feat_nc, W1p, W2p, idx, W1, W3, g1, b1, g2, b2, g3, b3, out);
}

// Round 5
// 210.927 us; speedup vs baseline: 7.1683x; 1.4035x over previous
//
#include <hip/hip_runtime.h>
#include <math.h>

typedef _Float16 f16;
typedef _Float16 f16x8 __attribute__((ext_vector_type(8)));
typedef float f32x4 __attribute__((ext_vector_type(4)));

#define B_  4
#define N_  2048
#define C_  128
#define NS_ 64

// ---- workspace layout (bytes) ----
#define WS_FEATNC 0u          // B*N*C f32 = 4194304
#define WS_IDX    4194304u    // B*N*NS u16 = 1048576
#define WS_W1P    5242880u    // 16 slices * 8192 = 131072
#define WS_W2P    5373952u    // 16 slices * 8192 = 131072

// ---- mlp LDS layout (bytes), total 51200 -> target 3 blocks/CU ----
#define OFF_H   0             // h 8 groups x 4096 = 32768; a1 halves overlay; a2 (33792) overlays H+W
#define OFF_W   32768         // weight dbuf 2 x 8192
#define OFF_GX  49152         // [64][3] f32 = 768
#define OFF_QF  49920         // [128] f32 = 512
#define OFF_IDX 50432         // 256 (RED overlays after gather)
#define OFF_RED 50432
#define OFF_W3  50688         // 512
#define LDS_TOTAL 51200

// K-slot permutation within a 16-group (consistent across h, a1, W1, W2)
#define SLOT(x) ((((x) & 3) << 2) | (((x) >> 2) & 3))

__device__ __forceinline__ void gl_lds16(const char* gp, char* lp) {
  __builtin_amdgcn_global_load_lds(
      (const __attribute__((address_space(1))) unsigned int*)gp,
      (__attribute__((address_space(3))) unsigned int*)lp, 16, 0, 0);
}

// activations: (hi, lo) error-compensated pair
__device__ __forceinline__ unsigned packpair(float v) {
  f16 hi = (f16)v;
  float r = (float)hi;
  f16 lo = (f16)(v - r);
  union { f16 h[2]; unsigned u; } cv;
  cv.h[0] = hi; cv.h[1] = lo;
  return cv.u;
}

// weights: duplicated (w, w) -> one MFMA gives (hi+lo)*w
__device__ __forceinline__ unsigned packdup(float v) {
  f16 h = (f16)v;
  union { f16 h2[2]; unsigned u; } cv;
  cv.h2[0] = h; cv.h2[1] = h;
  return cv.u;
}

// ---------------------------------------------------------------------------
// prep: feat (B,C,N)->(B,N,C) f32; W1 feature-cols -> 16 slices (g,oh)
// [128 o'][16 slot] dup-packed swizzled; W2 -> 16 o-slices [128 p][16 slot].
// Images are exact LDS bytes: mlp stages them with linear global_load_lds.
// ---------------------------------------------------------------------------
__global__ __launch_bounds__(256) void prep_kernel(
    const float* __restrict__ feat, const float* __restrict__ W1,
    const float* __restrict__ W2, float* __restrict__ feat_nc,
    char* __restrict__ W1p, char* __restrict__ W2p)
{
  int i = blockIdx.x * 256 + threadIdx.x;
  {
    int n = i & (N_ - 1);
    int bc = i >> 11;
    int c = bc & (C_ - 1);
    int b = bc >> 7;
    feat_nc[(size_t)((b << 11) + n) * C_ + c] = feat[i];
  }
  if (i < 16 * 2048) {   // W1: sl = g*2+oh; [o' 0..127][cl 0..15]; c = 3 + g*16+cl
    int sl = i >> 11; int r = i & 2047; int op = r >> 4; int cl = r & 15;
    int g = sl >> 1, oh = sl & 1;
    int o = oh * 128 + op;
    float wv = W1[o * 131 + 3 + g * 16 + cl];
    unsigned byte = ((unsigned)(op * 64 + SLOT(cl) * 4)) ^ ((unsigned)(((op >> 1) & 7) << 4));
    *(unsigned*)(W1p + (size_t)sl * 8192 + byte) = packdup(wv);
  }
  if (i < 16 * 2048) {   // W2: ko slices over o; [p 0..127][ol 0..15]
    int ko = i >> 11; int r = i & 2047; int p = r >> 4; int ol = r & 15;
    int o = ko * 16 + ol;
    float wv = W2[p * 256 + o];
    unsigned byte = ((unsigned)(p * 64 + SLOT(ol) * 4)) ^ ((unsigned)(((p >> 1) & 7) << 4));
    *(unsigned*)(W2p + (size_t)ko * 8192 + byte) = packdup(wv);
  }
}

// ---------------------------------------------------------------------------
// ball query (fp64-exact membership), output u16
// ---------------------------------------------------------------------------
__global__ __launch_bounds__(256) void ballquery_kernel(
    const float* __restrict__ xyz, unsigned short* __restrict__ idxout)
{
  __shared__ float  xl[N_ * 3];
  __shared__ double sq[N_];
  __shared__ int    ibuf[4][NS_];

  const int b  = blockIdx.x >> 9;
  const int ng = blockIdx.x & 511;
  const int t  = threadIdx.x;
  const float* xb = xyz + (size_t)b * N_ * 3;

  for (int i = t; i < N_ * 3; i += 256) xl[i] = xb[i];
  __syncthreads();
  for (int i = t; i < N_; i += 256) {
    double x = (double)xl[3*i], y = (double)xl[3*i+1], z = (double)xl[3*i+2];
    sq[i] = x*x + y*y + z*z;
  }
  __syncthreads();

  const int wv = t >> 6, lane = t & 63;
  const int n = ng * 4 + wv;
  const double xn = (double)xl[3*n], yn = (double)xl[3*n+1], zn = (double)xl[3*n+2];
  const double sn = sq[n];

  int cnt = 0;
  for (int mb = 0; mb < N_; mb += 64) {
    int m = mb + lane;
    double dot = xn*(double)xl[3*m] + yn*(double)xl[3*m+1] + zn*(double)xl[3*m+2];
    double d2 = (sn + sq[m]) - 2.0 * dot;
    bool hit = d2 < 0.0625;
    unsigned long long mask = __ballot(hit);
    int pos = __popcll(mask & ((1ULL << lane) - 1ULL));
    int slot = cnt + pos;
    if (hit && slot < NS_) ibuf[wv][slot] = m;
    cnt += (int)__popcll(mask);
    if (cnt >= NS_) break;
  }
  asm volatile("s_waitcnt lgkmcnt(0)" ::: "memory");
  int total = cnt < NS_ ? cnt : NS_;
  int v = ibuf[wv][lane < total ? lane : 0];
  idxout[((size_t)b * N_ + n) * NS_ + lane] = (unsigned short)v;
}

// ---------------------------------------------------------------------------
// MLP: f16 MFMA; activations = (hi,lo) pairs, weights = (w,w) duplicated ->
// 1 MFMA per K-slice (exact activation x f16-truncated weight). xyz channels
// on VALU (acc1 init). 51200B LDS -> 3 blocks/CU. GEMM1: 16 phases; GEMM2:
// 16 phases with a1 K-half split. Depth-1 dbuf via global_load_lds.
// ---------------------------------------------------------------------------
__global__ __launch_bounds__(256, 3) void mlp_kernel(
    const float* __restrict__ xyz, const float* __restrict__ feat_nc,
    const char* __restrict__ w1p, const char* __restrict__ w2p,
    const unsigned short* __restrict__ idxg,
    const float* __restrict__ W1g, const float* __restrict__ W3g,
    const float* __restrict__ g1, const float* __restrict__ b1,
    const float* __restrict__ g2, const float* __restrict__ b2,
    const float* __restrict__ g3, const float* __restrict__ b3,
    float* __restrict__ out)
{
  __shared__ __attribute__((aligned(128))) char lds[LDS_TOTAL];

  const int bidRaw = blockIdx.x;
  const int bn = ((bidRaw & 7) << 10) + (bidRaw >> 3);   // XCD swizzle (bijective)
  const int b = bn >> 11;
  const int n = bn & (N_ - 1);
  const int t = threadIdx.x;
  const int w = t >> 6, lane = t & 63;
  const int l15 = lane & 15, lg = lane >> 4;
  const unsigned labase = ((unsigned)(l15 * 64 + lg * 16)) ^ ((unsigned)(((l15 >> 1) & 7) << 4));
  const float inv = 1.0f / sqrtf(1.0f + 1e-5f);

  float gg1v[4], bo1v[4];
  float wx[4][3];
  #pragma unroll
  for (int nt = 0; nt < 4; ++nt) {
    int o = (nt >> 1) * 128 + 32 * w + (nt & 1) * 16 + l15;
    gg1v[nt] = g1[o] * inv; bo1v[nt] = b1[o];
    #pragma unroll
    for (int c = 0; c < 3; ++c) wx[nt][c] = W1g[o * 131 + c];
  }
  float gg2v[2], bo2v[2];
  #pragma unroll
  for (int nt = 0; nt < 2; ++nt) {
    int p = 32 * w + nt * 16 + l15;
    gg2v[nt] = g2[p] * inv; bo2v[nt] = b2[p];
  }
  const float g3c = g3[0] * inv, b3c = b3[0];
  const float xn0 = xyz[(size_t)bn*3+0], xn1 = xyz[(size_t)bn*3+1], xn2 = xyz[(size_t)bn*3+2];

  auto STAGE = [&](int sl) {
    const char* gp = (sl < 16 ? w1p + (size_t)sl * 8192
                              : w2p + (size_t)(sl - 16) * 8192) + t * 16;
    char* lp = lds + OFF_W + ((sl & 1) << 13) + (w << 10);
    gl_lds16(gp, lp);
    gl_lds16(gp + 4096, lp + 4096);
  };

  f32x4 acc1[4][4];
  f32x4 acc2[4][2] = {};

  // ---- prologue ----
  STAGE(0);
  if (t < 64) ((int*)(lds + OFF_IDX))[t] = (int)idxg[(size_t)bn * 64 + t];
  if (t < 128) ((float*)(lds + OFF_QF))[t] = feat_nc[(size_t)bn * C_ + t];
  if (t < 128) ((float*)(lds + OFF_W3))[t] = W3g[t];
  __syncthreads();

  const int* idxl = (const int*)(lds + OFF_IDX);
  const float* qf = (const float*)(lds + OFF_QF);

  // gather features -> h pair-packed (conflict-free via SLOT + group-XOR)
  #pragma unroll
  for (int k = 0; k < 8; ++k) {
    int i = t + k * 256;
    int s = i >> 5, q4 = i & 31;
    int m = idxl[s];
    f32x4 f = *(const f32x4*)(feat_nc + ((size_t)b * N_ + m) * C_ + q4 * 4);
    unsigned sw = ((unsigned)((s >> 1) & 7)) << 4;
    #pragma unroll
    for (int e = 0; e < 4; ++e) {
      int j = q4 * 4 + e;
      float d = f[e] - qf[j];
      int g = j >> 4;
      unsigned byte = (unsigned)(g * 4096)
        + ((((unsigned)(s * 64 + SLOT(j & 15) * 4)) ^ sw ^ ((unsigned)((g & 7) << 4))));
      *(unsigned*)(lds + OFF_H + byte) = packpair(d * d);
    }
  }
  // gather xyz -> GX (relative coords; also feeds VALU z1 contribution)
  if (t < 192) {
    int s = t & 63, c = t >> 6;
    int m = idxl[s];
    float p = xyz[((size_t)b * N_ + m) * 3 + c];
    float xnc = (c == 0) ? xn0 : (c == 1 ? xn1 : xn2);
    ((float*)(lds + OFF_GX))[s * 3 + c] = p - xnc;
  }
  asm volatile("s_waitcnt vmcnt(0)" ::: "memory");
  __syncthreads();

  // ---- xyz-channel contribution: acc1 init on VALU (h_xyz = (p - 2*xn)^2) ----
  {
    const float* gx = (const float*)(lds + OFF_GX);
    #pragma unroll
    for (int mt = 0; mt < 4; ++mt)
      #pragma unroll
      for (int r = 0; r < 4; ++r) {
        int s = mt * 16 + lg * 4 + r;
        float d0 = gx[s * 3 + 0] - xn0;
        float d1 = gx[s * 3 + 1] - xn1;
        float d2 = gx[s * 3 + 2] - xn2;
        d0 *= d0; d1 *= d1; d2 *= d2;
        #pragma unroll
        for (int nt = 0; nt < 4; ++nt)
          acc1[mt][nt][r] = fmaf(wx[nt][0], d0, fmaf(wx[nt][1], d1, wx[nt][2] * d2));
      }
  }

  // ---- GEMM1: 16 phases (g 0..7 x oh 0..1), 1 MFMA per position ----
  f16x8 af[4];
  #pragma unroll
  for (int p = 0; p < 16; ++p) {
    const int g = p >> 1, oh = p & 1;
    STAGE(p + 1);
    if (oh == 0) {
      const char* hb = lds + OFF_H + g * 4096;
      const unsigned gx4 = ((unsigned)(g & 7)) << 4;
      #pragma unroll
      for (int mt = 0; mt < 4; ++mt)
        af[mt] = *(const f16x8*)(hb + mt * 1024 + (labase ^ gx4));
    }
    const char* wb = lds + OFF_W + ((p & 1) << 13);
    f16x8 bf0 = *(const f16x8*)(wb + (32 * w) * 64 + labase);
    f16x8 bf1 = *(const f16x8*)(wb + (32 * w + 16) * 64 + labase);
    __builtin_amdgcn_s_setprio(1);
    #pragma unroll
    for (int mt = 0; mt < 4; ++mt) {
      acc1[mt][oh * 2 + 0] =
          __builtin_amdgcn_mfma_f32_16x16x32_f16(af[mt], bf0, acc1[mt][oh * 2 + 0], 0, 0, 0);
      acc1[mt][oh * 2 + 1] =
          __builtin_amdgcn_mfma_f32_16x16x32_f16(af[mt], bf1, acc1[mt][oh * 2 + 1], 0, 0, 0);
    }
    __builtin_amdgcn_s_setprio(0);
    asm volatile("s_waitcnt vmcnt(0)" ::: "memory");
    __syncthreads();
  }

  // ---- epilogue1: a1 half -> h region (pair-packed, swizzled) ----
  auto EPI1 = [&](int hf) {
    const unsigned slotl = (unsigned)SLOT(l15);
    #pragma unroll
    for (int mt = 0; mt < 4; ++mt)
      #pragma unroll
      for (int nt2 = 0; nt2 < 2; ++nt2) {
        const int nt = hf * 2 + nt2;
        const int ga = 2 * w + nt2;
        #pragma unroll
        for (int r = 0; r < 4; ++r) {
          int s = mt * 16 + lg * 4 + r;
          float a = fmaf(acc1[mt][nt][r], gg1v[nt], bo1v[nt]);
          a = a > 0.0f ? a : 0.0f;
          unsigned byte = (unsigned)(ga * 4096)
            + ((((unsigned)(s * 64) + slotl * 4)) ^ ((unsigned)(((s >> 1) & 7) << 4))
               ^ ((unsigned)((ga & 7) << 4)));
          *(unsigned*)(lds + OFF_H + byte) = packpair(a);
        }
      }
  };
  EPI1(0);
  __syncthreads();

  // ---- GEMM2: 16 phases, a1 half-split at ko==8, 1 MFMA per position ----
  #pragma unroll
  for (int ko = 0; ko < 16; ++ko) {
    if (ko < 15) STAGE(17 + ko);
    const char* ab = lds + OFF_H + (ko & 7) * 4096;
    const unsigned gx4 = ((unsigned)(ko & 7)) << 4;
    f16x8 a2f[4];
    #pragma unroll
    for (int mt = 0; mt < 4; ++mt)
      a2f[mt] = *(const f16x8*)(ab + mt * 1024 + (labase ^ gx4));
    const char* wb = lds + OFF_W + ((ko & 1) << 13);
    f16x8 bf0 = *(const f16x8*)(wb + (32 * w) * 64 + labase);
    f16x8 bf1 = *(const f16x8*)(wb + (32 * w + 16) * 64 + labase);
    __builtin_amdgcn_s_setprio(1);
    #pragma unroll
    for (int mt = 0; mt < 4; ++mt) {
      acc2[mt][0] =
          __builtin_amdgcn_mfma_f32_16x16x32_f16(a2f[mt], bf0, acc2[mt][0], 0, 0, 0);
      acc2[mt][1] =
          __builtin_amdgcn_mfma_f32_16x16x32_f16(a2f[mt], bf1, acc2[mt][1], 0, 0, 0);
    }
    __builtin_amdgcn_s_setprio(0);
    asm volatile("s_waitcnt vmcnt(0)" ::: "memory");
    __syncthreads();
    if (ko == 7) {       // a1 half0 consumed -> write half1
      EPI1(1);
      __syncthreads();
    }
  }

  // ---- epilogue2: a2 = relu(bn2(z2)) f32, rows stride 528B (overlays H+W) ----
  #pragma unroll
  for (int mt = 0; mt < 4; ++mt)
    #pragma unroll
    for (int nt2 = 0; nt2 < 2; ++nt2) {
      int p2 = 32 * w + nt2 * 16 + l15;
      #pragma unroll
      for (int r = 0; r < 4; ++r) {
        int s = mt * 16 + lg * 4 + r;
        float a = fmaf(acc2[mt][nt2][r], gg2v[nt2], bo2v[nt2]);
        a = a > 0.0f ? a : 0.0f;
        *(float*)(lds + s * 528 + p2 * 4) = a;
      }
    }
  __syncthreads();

  // ---- GEMM3 + weighted mean ----
  {
    int s3 = t >> 2, q3 = t & 3;
    const float* a2row = (const float*)lds + s3 * 132;
    const float* w3r = (const float*)(lds + OFF_W3);
    float z3 = 0.0f;
    #pragma unroll
    for (int i = 0; i < 8; ++i) {
      f32x4 av = *(const f32x4*)(a2row + q3 * 32 + i * 4);
      f32x4 wv = *(const f32x4*)(w3r + q3 * 32 + i * 4);
      z3 = fmaf(av[0], wv[0], z3); z3 = fmaf(av[1], wv[1], z3);
      z3 = fmaf(av[2], wv[2], z3); z3 = fmaf(av[3], wv[3], z3);
    }
    z3 += __shfl_xor(z3, 1);
    z3 += __shfl_xor(z3, 2);
    float wgt = fmaf(g3c, z3, b3c);
    wgt = wgt > 0.0f ? wgt : 0.0f;
    float v0 = 0.f, v1 = 0.f, v2 = 0.f, v3 = 0.f;
    if (q3 == 0) {
      const float* gx = (const float*)(lds + OFF_GX) + s3 * 3;
      v0 = gx[0] * wgt; v1 = gx[1] * wgt; v2 = gx[2] * wgt; v3 = wgt;
    }
    #pragma unroll
    for (int off = 4; off < 64; off <<= 1) {
      v0 += __shfl_xor(v0, off); v1 += __shfl_xor(v1, off);
      v2 += __shfl_xor(v2, off); v3 += __shfl_xor(v3, off);
    }
    if (lane == 0) {
      float* red = (float*)(lds + OFF_RED);
      red[w * 4 + 0] = v0; red[w * 4 + 1] = v1;
      red[w * 4 + 2] = v2; red[w * 4 + 3] = v3;
    }
    __syncthreads();
    if (t == 0) {
      const float* red = (const float*)(lds + OFF_RED);
      float n0 = red[0] + red[4] + red[8]  + red[12];
      float n1 = red[1] + red[5] + red[9]  + red[13];
      float n2 = red[2] + red[6] + red[10] + red[14];
      float dd = red[3] + red[7] + red[11] + red[15];
      out[(size_t)(b * 3 + 0) * N_ + n] = n0 / dd;
      out[(size_t)(b * 3 + 1) * N_ + n] = n1 / dd;
      out[(size_t)(b * 3 + 2) * N_ + n] = n2 / dd;
    }
  }
}

extern "C" void kernel_launch(void* const* d_in, const int* in_sizes, int n_in,
                              void* d_out, int out_size, void* d_ws, size_t ws_size,
                              hipStream_t stream) {
  (void)in_sizes; (void)n_in; (void)out_size; (void)ws_size;
  const float* xyz      = (const float*)d_in[0];
  const float* features = (const float*)d_in[1];
  const float* W1 = (const float*)d_in[2];
  const float* W2 = (const float*)d_in[3];
  const float* W3 = (const float*)d_in[4];
  const float* g1 = (const float*)d_in[5];
  const float* g2 = (const float*)d_in[6];
  const float* g3 = (const float*)d_in[7];
  const float* b1 = (const float*)d_in[8];
  const float* b2 = (const float*)d_in[9];
  const float* b3 = (const float*)d_in[10];
  float* out = (float*)d_out;

  char* ws = (char*)d_ws;
  float* feat_nc      = (float*)(ws + WS_FEATNC);
  unsigned short* idx = (unsigned short*)(ws + WS_IDX);
  char* W1p           = ws + WS_W1P;
  char* W2p           = ws + WS_W2P;

  prep_kernel<<<dim3((B_ * C_ * N_) / 256), dim3(256), 0, stream>>>(
      features, W1, W2, feat_nc, W1p, W2p);
  ballquery_kernel<<<dim3(B_ * N_ / 4), dim3(256), 0, stream>>>(xyz, idx);
  mlp_kernel<<<dim3(B_ * N_), dim3(256), 0, stream>>>(
      xyz, feat_nc, W1p, W2p, idx, W1, W3, g1, b1, g2, b2, g3, b3, out);
}

// Round 6
// 170.896 us; speedup vs baseline: 8.8474x; 1.2342x over previous
//
#include <hip/hip_runtime.h>
#include <math.h>

typedef _Float16 f16;
typedef _Float16 f16x8 __attribute__((ext_vector_type(8)));
typedef float f32x4 __attribute__((ext_vector_type(4)));
typedef unsigned u32x2 __attribute__((ext_vector_type(2)));

#define B_  4
#define N_  2048
#define C_  128
#define NS_ 64

// ---- workspace layout (bytes) ----
#define WS_FEATNC 0u          // B*N*C f32 = 4194304
#define WS_IDX    4194304u    // B*N*NS u16 = 1048576
#define WS_W1P    5242880u    // 8 slices * 8192 = 65536
#define WS_W2P    5308416u    // 8 slices * 8192 = 65536

// ---- mlp LDS layout (bytes), total 35840 -> 4 blocks/CU ----
#define OFF_H   0             // h: 4 groups x 4096 = 16384 (a1 halves overlay)
#define OFF_W   16384         // weight dbuf 2 x 8192
#define OFF_A2  0             // 64*132*4 = 33792 f32 (overlays H+W at the end)
#define OFF_GX  33792         // [64][3] f32 = 768
#define OFF_QF  34560         // [128] f32 = 512
#define OFF_IDX 35072         // 256 (RED overlays after gather)
#define OFF_RED 35072
#define OFF_W3  35328         // 512
#define LDS_TOTAL 35840

__device__ __forceinline__ void gl_lds16(const char* gp, char* lp) {
  __builtin_amdgcn_global_load_lds(
      (const __attribute__((address_space(1))) unsigned int*)gp,
      (__attribute__((address_space(3))) unsigned int*)lp, 16, 0, 0);
}

// pack two floats as adjacent f16 (RTN)
__device__ __forceinline__ unsigned pk2(float a, float b) {
  union { f16 h[2]; unsigned u; } cv;
  cv.h[0] = (f16)a; cv.h[1] = (f16)b;
  return cv.u;
}

// ---------------------------------------------------------------------------
// prep: feat (B,C,N)->(B,N,C) f32; W1 feature-cols -> 8 slices (g 0..3, oh
// 0..1): [128 o'][16 ch-pair slots] f16 swizzled; W2 -> 8 o-slices [128 p]
// [16 slots]. Images are exact LDS bytes for linear global_load_lds staging.
// ---------------------------------------------------------------------------
__global__ __launch_bounds__(256) void prep_kernel(
    const float* __restrict__ feat, const float* __restrict__ W1,
    const float* __restrict__ W2, float* __restrict__ feat_nc,
    char* __restrict__ W1p, char* __restrict__ W2p)
{
  int i = blockIdx.x * 256 + threadIdx.x;
  {
    int n = i & (N_ - 1);
    int bc = i >> 11;
    int c = bc & (C_ - 1);
    int b = bc >> 7;
    feat_nc[(size_t)((b << 11) + n) * C_ + c] = feat[i];
  }
  if (i < 8 * 2048) {   // W1: sl = g*2+oh; [o' 0..127][j 0..15]; ch = g*32+2j
    int sl = i >> 11; int r = i & 2047; int op = r >> 4; int j = r & 15;
    int g = sl >> 1, oh = sl & 1;
    int o = oh * 128 + op;
    const float* row = W1 + o * 131 + 3 + g * 32 + 2 * j;
    unsigned byte = ((unsigned)(op * 64 + j * 4)) ^ ((unsigned)(((op >> 1) & 7) << 4));
    *(unsigned*)(W1p + (size_t)sl * 8192 + byte) = pk2(row[0], row[1]);
  }
  if (i < 8 * 2048) {   // W2: ko slices; [p 0..127][j 0..15]; o = ko*32+2j
    int ko = i >> 11; int r = i & 2047; int p = r >> 4; int j = r & 15;
    int o = ko * 32 + 2 * j;
    unsigned byte = ((unsigned)(p * 64 + j * 4)) ^ ((unsigned)(((p >> 1) & 7) << 4));
    *(unsigned*)(W2p + (size_t)ko * 8192 + byte) = pk2(W2[p * 256 + o], W2[p * 256 + o + 1]);
  }
}

// ---------------------------------------------------------------------------
// ball query (fp64-exact membership), output u16
// ---------------------------------------------------------------------------
__global__ __launch_bounds__(256) void ballquery_kernel(
    const float* __restrict__ xyz, unsigned short* __restrict__ idxout)
{
  __shared__ float  xl[N_ * 3];
  __shared__ double sq[N_];
  __shared__ int    ibuf[4][NS_];

  const int b  = blockIdx.x >> 9;
  const int ng = blockIdx.x & 511;
  const int t  = threadIdx.x;
  const float* xb = xyz + (size_t)b * N_ * 3;

  for (int i = t; i < N_ * 3; i += 256) xl[i] = xb[i];
  __syncthreads();
  for (int i = t; i < N_; i += 256) {
    double x = (double)xl[3*i], y = (double)xl[3*i+1], z = (double)xl[3*i+2];
    sq[i] = x*x + y*y + z*z;
  }
  __syncthreads();

  const int wv = t >> 6, lane = t & 63;
  const int n = ng * 4 + wv;
  const double xn = (double)xl[3*n], yn = (double)xl[3*n+1], zn = (double)xl[3*n+2];
  const double sn = sq[n];

  int cnt = 0;
  for (int mb = 0; mb < N_; mb += 64) {
    int m = mb + lane;
    double dot = xn*(double)xl[3*m] + yn*(double)xl[3*m+1] + zn*(double)xl[3*m+2];
    double d2 = (sn + sq[m]) - 2.0 * dot;
    bool hit = d2 < 0.0625;
    unsigned long long mask = __ballot(hit);
    int pos = __popcll(mask & ((1ULL << lane) - 1ULL));
    int slot = cnt + pos;
    if (hit && slot < NS_) ibuf[wv][slot] = m;
    cnt += (int)__popcll(mask);
    if (cnt >= NS_) break;
  }
  asm volatile("s_waitcnt lgkmcnt(0)" ::: "memory");
  int total = cnt < NS_ ? cnt : NS_;
  int v = ibuf[wv][lane < total ? lane : 0];
  idxout[((size_t)b * N_ + n) * NS_ + lane] = (unsigned short)v;
}

// ---------------------------------------------------------------------------
// MLP: pure-f16 MFMA (activations + weights single f16, fp32 accumulate).
// GEMM1 K=128 (8 phases: 4 ch-groups x 2 o-halves); GEMM2 K=256 (8 phases,
// a1 half-split). xyz channels on VALU (fp32-exact acc1 init). 35840B LDS ->
// 4 blocks/CU. Depth-1 weight dbuf via global_load_lds.
// ---------------------------------------------------------------------------
__global__ __launch_bounds__(256, 4) void mlp_kernel(
    const float* __restrict__ xyz, const float* __restrict__ feat_nc,
    const char* __restrict__ w1p, const char* __restrict__ w2p,
    const unsigned short* __restrict__ idxg,
    const float* __restrict__ W1g, const float* __restrict__ W3g,
    const float* __restrict__ g1, const float* __restrict__ b1,
    const float* __restrict__ g2, const float* __restrict__ b2,
    const float* __restrict__ g3, const float* __restrict__ b3,
    float* __restrict__ out)
{
  __shared__ __attribute__((aligned(128))) char lds[LDS_TOTAL];

  const int bidRaw = blockIdx.x;
  const int bn = ((bidRaw & 7) << 10) + (bidRaw >> 3);   // XCD swizzle (bijective)
  const int b = bn >> 11;
  const int n = bn & (N_ - 1);
  const int t = threadIdx.x;
  const int w = t >> 6, lane = t & 63;
  const int l15 = lane & 15, lg = lane >> 4;
  const unsigned labase = ((unsigned)(l15 * 64 + lg * 16)) ^ ((unsigned)(((l15 >> 1) & 7) << 4));
  const float inv = 1.0f / sqrtf(1.0f + 1e-5f);

  float gg1v[4], bo1v[4];
  float wx[4][3];
  #pragma unroll
  for (int nt = 0; nt < 4; ++nt) {
    int o = (nt >> 1) * 128 + 32 * w + (nt & 1) * 16 + l15;
    gg1v[nt] = g1[o] * inv; bo1v[nt] = b1[o];
    #pragma unroll
    for (int c = 0; c < 3; ++c) wx[nt][c] = W1g[o * 131 + c];
  }
  float gg2v[2], bo2v[2];
  #pragma unroll
  for (int nt = 0; nt < 2; ++nt) {
    int p = 32 * w + nt * 16 + l15;
    gg2v[nt] = g2[p] * inv; bo2v[nt] = b2[p];
  }
  const float g3c = g3[0] * inv, b3c = b3[0];
  const float xn0 = xyz[(size_t)bn*3+0], xn1 = xyz[(size_t)bn*3+1], xn2 = xyz[(size_t)bn*3+2];

  auto STAGE = [&](int sl) {
    const char* gp = (sl < 8 ? w1p + (size_t)sl * 8192
                             : w2p + (size_t)(sl - 8) * 8192) + t * 16;
    char* lp = lds + OFF_W + ((sl & 1) << 13) + (w << 10);
    gl_lds16(gp, lp);
    gl_lds16(gp + 4096, lp + 4096);
  };

  f32x4 acc1[4][4];
  f32x4 acc2[4][2] = {};

  // ---- prologue ----
  STAGE(0);
  if (t < 64) ((int*)(lds + OFF_IDX))[t] = (int)idxg[(size_t)bn * 64 + t];
  if (t < 128) ((float*)(lds + OFF_QF))[t] = feat_nc[(size_t)bn * C_ + t];
  if (t < 128) ((float*)(lds + OFF_W3))[t] = W3g[t];
  __syncthreads();

  const int* idxl = (const int*)(lds + OFF_IDX);
  const float* qf = (const float*)(lds + OFF_QF);

  // gather features -> h f16 (4 channels per b64 write)
  #pragma unroll
  for (int k = 0; k < 8; ++k) {
    int i = t + k * 256;
    int s = i >> 5, q4 = i & 31;
    int m = idxl[s];
    f32x4 f = *(const f32x4*)(feat_nc + ((size_t)b * N_ + m) * C_ + q4 * 4);
    int j4 = q4 * 4;
    float d0 = f[0] - qf[j4 + 0];
    float d1 = f[1] - qf[j4 + 1];
    float d2 = f[2] - qf[j4 + 2];
    float d3 = f[3] - qf[j4 + 3];
    int g = q4 >> 3;
    unsigned byte = (unsigned)(g * 4096)
      + (((unsigned)(s * 64 + (q4 & 7) * 8)) ^ ((unsigned)(((s >> 1) & 7) << 4))
         ^ ((unsigned)((g & 3) << 4)));
    u32x2 v;
    v.x = pk2(d0 * d0, d1 * d1);
    v.y = pk2(d2 * d2, d3 * d3);
    *(u32x2*)(lds + OFF_H + byte) = v;
  }
  // gather xyz -> GX (relative coords; also feeds VALU z1 contribution)
  if (t < 192) {
    int s = t & 63, c = t >> 6;
    int m = idxl[s];
    float p = xyz[((size_t)b * N_ + m) * 3 + c];
    float xnc = (c == 0) ? xn0 : (c == 1 ? xn1 : xn2);
    ((float*)(lds + OFF_GX))[s * 3 + c] = p - xnc;
  }
  asm volatile("s_waitcnt vmcnt(0)" ::: "memory");
  __syncthreads();

  // ---- xyz-channel contribution: acc1 init on VALU (h_xyz = (p - 2*xn)^2) ----
  {
    const float* gx = (const float*)(lds + OFF_GX);
    #pragma unroll
    for (int mt = 0; mt < 4; ++mt)
      #pragma unroll
      for (int r = 0; r < 4; ++r) {
        int s = mt * 16 + lg * 4 + r;
        float d0 = gx[s * 3 + 0] - xn0;
        float d1 = gx[s * 3 + 1] - xn1;
        float d2 = gx[s * 3 + 2] - xn2;
        d0 *= d0; d1 *= d1; d2 *= d2;
        #pragma unroll
        for (int nt = 0; nt < 4; ++nt)
          acc1[mt][nt][r] = fmaf(wx[nt][0], d0, fmaf(wx[nt][1], d1, wx[nt][2] * d2));
      }
  }

  // ---- GEMM1: 8 phases (g 0..3 x oh 0..1) ----
  f16x8 af[4];
  #pragma unroll
  for (int p = 0; p < 8; ++p) {
    const int g = p >> 1, oh = p & 1;
    STAGE(p + 1);
    if (oh == 0) {
      const char* hb = lds + OFF_H + g * 4096;
      const unsigned gx4 = ((unsigned)(g & 3)) << 4;
      #pragma unroll
      for (int mt = 0; mt < 4; ++mt)
        af[mt] = *(const f16x8*)(hb + mt * 1024 + (labase ^ gx4));
    }
    const char* wb = lds + OFF_W + ((p & 1) << 13);
    f16x8 bf0 = *(const f16x8*)(wb + (32 * w) * 64 + labase);
    f16x8 bf1 = *(const f16x8*)(wb + (32 * w + 16) * 64 + labase);
    __builtin_amdgcn_s_setprio(1);
    #pragma unroll
    for (int mt = 0; mt < 4; ++mt) {
      acc1[mt][oh * 2 + 0] =
          __builtin_amdgcn_mfma_f32_16x16x32_f16(af[mt], bf0, acc1[mt][oh * 2 + 0], 0, 0, 0);
      acc1[mt][oh * 2 + 1] =
          __builtin_amdgcn_mfma_f32_16x16x32_f16(af[mt], bf1, acc1[mt][oh * 2 + 1], 0, 0, 0);
    }
    __builtin_amdgcn_s_setprio(0);
    asm volatile("s_waitcnt vmcnt(0)" ::: "memory");
    __syncthreads();
  }

  // ---- epilogue1: a1 (f16 singles) -> h region; wave w owns o-group w ----
  auto EPI1 = [&](int hf) {
    #pragma unroll
    for (int mt = 0; mt < 4; ++mt)
      #pragma unroll
      for (int nt2 = 0; nt2 < 2; ++nt2) {
        const int nt = hf * 2 + nt2;
        #pragma unroll
        for (int r = 0; r < 4; ++r) {
          int s = mt * 16 + lg * 4 + r;
          float a = fmaf(acc1[mt][nt][r], gg1v[nt], bo1v[nt]);
          a = a > 0.0f ? a : 0.0f;
          unsigned byte = (unsigned)(w * 4096)
            + (((unsigned)(s * 64 + nt2 * 32 + l15 * 2)) ^ ((unsigned)(((s >> 1) & 7) << 4))
               ^ ((unsigned)((w & 3) << 4)));
          *(f16*)(lds + OFF_H + byte) = (f16)a;
        }
      }
  };
  EPI1(0);
  __syncthreads();

  // ---- GEMM2: 8 phases, a1 half-split at ko==4 ----
  #pragma unroll
  for (int ko = 0; ko < 8; ++ko) {
    if (ko < 7) STAGE(9 + ko);
    const char* ab = lds + OFF_H + (ko & 3) * 4096;
    const unsigned gx4 = ((unsigned)(ko & 3)) << 4;
    f16x8 a2f[4];
    #pragma unroll
    for (int mt = 0; mt < 4; ++mt)
      a2f[mt] = *(const f16x8*)(ab + mt * 1024 + (labase ^ gx4));
    const char* wb = lds + OFF_W + ((ko & 1) << 13);
    f16x8 bf0 = *(const f16x8*)(wb + (32 * w) * 64 + labase);
    f16x8 bf1 = *(const f16x8*)(wb + (32 * w + 16) * 64 + labase);
    __builtin_amdgcn_s_setprio(1);
    #pragma unroll
    for (int mt = 0; mt < 4; ++mt) {
      acc2[mt][0] =
          __builtin_amdgcn_mfma_f32_16x16x32_f16(a2f[mt], bf0, acc2[mt][0], 0, 0, 0);
      acc2[mt][1] =
          __builtin_amdgcn_mfma_f32_16x16x32_f16(a2f[mt], bf1, acc2[mt][1], 0, 0, 0);
    }
    __builtin_amdgcn_s_setprio(0);
    asm volatile("s_waitcnt vmcnt(0)" ::: "memory");
    __syncthreads();
    if (ko == 3) {       // a1 half0 consumed -> write half1
      EPI1(1);
      __syncthreads();
    }
  }

  // ---- epilogue2: a2 = relu(bn2(z2)) f32, rows stride 528B (overlays H+W) ----
  #pragma unroll
  for (int mt = 0; mt < 4; ++mt)
    #pragma unroll
    for (int nt2 = 0; nt2 < 2; ++nt2) {
      int p2 = 32 * w + nt2 * 16 + l15;
      #pragma unroll
      for (int r = 0; r < 4; ++r) {
        int s = mt * 16 + lg * 4 + r;
        float a = fmaf(acc2[mt][nt2][r], gg2v[nt2], bo2v[nt2]);
        a = a > 0.0f ? a : 0.0f;
        *(float*)(lds + OFF_A2 + s * 528 + p2 * 4) = a;
      }
    }
  __syncthreads();

  // ---- GEMM3 + weighted mean ----
  {
    int s3 = t >> 2, q3 = t & 3;
    const float* a2row = (const float*)(lds + OFF_A2) + s3 * 132;
    const float* w3r = (const float*)(lds + OFF_W3);
    float z3 = 0.0f;
    #pragma unroll
    for (int i = 0; i < 8; ++i) {
      f32x4 av = *(const f32x4*)(a2row + q3 * 32 + i * 4);
      f32x4 wv = *(const f32x4*)(w3r + q3 * 32 + i * 4);
      z3 = fmaf(av[0], wv[0], z3); z3 = fmaf(av[1], wv[1], z3);
      z3 = fmaf(av[2], wv[2], z3); z3 = fmaf(av[3], wv[3], z3);
    }
    z3 += __shfl_xor(z3, 1);
    z3 += __shfl_xor(z3, 2);
    float wgt = fmaf(g3c, z3, b3c);
    wgt = wgt > 0.0f ? wgt : 0.0f;
    float v0 = 0.f, v1 = 0.f, v2 = 0.f, v3 = 0.f;
    if (q3 == 0) {
      const float* gx = (const float*)(lds + OFF_GX) + s3 * 3;
      v0 = gx[0] * wgt; v1 = gx[1] * wgt; v2 = gx[2] * wgt; v3 = wgt;
    }
    #pragma unroll
    for (int off = 4; off < 64; off <<= 1) {
      v0 += __shfl_xor(v0, off); v1 += __shfl_xor(v1, off);
      v2 += __shfl_xor(v2, off); v3 += __shfl_xor(v3, off);
    }
    if (lane == 0) {
      float* red = (float*)(lds + OFF_RED);
      red[w * 4 + 0] = v0; red[w * 4 + 1] = v1;
      red[w * 4 + 2] = v2; red[w * 4 + 3] = v3;
    }
    __syncthreads();
    if (t == 0) {
      const float* red = (const float*)(lds + OFF_RED);
      float n0 = red[0] + red[4] + red[8]  + red[12];
      float n1 = red[1] + red[5] + red[9]  + red[13];
      float n2 = red[2] + red[6] + red[10] + red[14];
      float dd = red[3] + red[7] + red[11] + red[15];
      out[(size_t)(b * 3 + 0) * N_ + n] = n0 / dd;
      out[(size_t)(b * 3 + 1) * N_ + n] = n1 / dd;
      out[(size_t)(b * 3 + 2) * N_ + n] = n2 / dd;
    }
  }
}

extern "C" void kernel_launch(void* const* d_in, const int* in_sizes, int n_in,
                              void* d_out, int out_size, void* d_ws, size_t ws_size,
                              hipStream_t stream) {
  (void)in_sizes; (void)n_in; (void)out_size; (void)ws_size;
  const float* xyz      = (const float*)d_in[0];
  const float* features = (const float*)d_in[1];
  const float* W1 = (const float*)d_in[2];
  const float* W2 = (const float*)d_in[3];
  const float* W3 = (const float*)d_in[4];
  const float* g1 = (const float*)d_in[5];
  const float* g2 = (const float*)d_in[6];
  const float* g3 = (const float*)d_in[7];
  const float* b1 = (const float*)d_in[8];
  const float* b2 = (const float*)d_in[9];
  const float* b3 = (const float*)d_in[10];
  float* out = (float*)d_out;

  char* ws = (char*)d_ws;
  float* feat_nc      = (float*)(ws + WS_FEATNC);
  unsigned short* idx = (unsigned short*)(ws + WS_IDX);
  char* W1p           = ws + WS_W1P;
  char* W2p           = ws + WS_W2P;

  prep_kernel<<<dim3((B_ * C_ * N_) / 256), dim3(256), 0, stream>>>(
      features, W1, W2, feat_nc, W1p, W2p);
  ballquery_kernel<<<dim3(B_ * N_ / 4), dim3(256), 0, stream>>>(xyz, idx);
  mlp_kernel<<<dim3(B_ * N_), dim3(256), 0, stream>>>(
      xyz, feat_nc, W1p, W2p, idx, W1, W3, g1, b1, g2, b2, g3, b3, out);
}